// Round 8
// baseline (223.305 us; speedup 1.0000x reference)
//
#include <hip/hip_runtime.h>
#include <hip/hip_bf16.h>
#include <cstdint>

#define B_ 4
#define T_ 2048
#define C_ 1024
#define H_ 16
#define D_ 64
#define NC_ 32   // chunks
#define L_ 64    // chunk length

typedef __attribute__((ext_vector_type(8))) short bf16x8;
typedef __attribute__((ext_vector_type(4))) float f32x4;

static __device__ __forceinline__ unsigned short f2bf(float f) {
  unsigned u = __float_as_uint(f);
  u += 0x7fff + ((u >> 16) & 1);   // round-to-nearest-even
  return (unsigned short)(u >> 16);
}
static __device__ __forceinline__ float bf2f(unsigned short b) {
  return __uint_as_float(((unsigned)b) << 16);
}
// XOR swizzle for 128B-stride LDS rows (T2): keeps 16B alignment, <=2-way conflicts
static __device__ __forceinline__ int swz128(int row, int byte) {
  return row * 128 + (byte ^ ((row & 7) << 4));
}

// Barrier that does NOT drain vmcnt (T4): LDS edges fenced via lgkmcnt(0).
#define LDS_BARRIER() asm volatile("s_waitcnt lgkmcnt(0)\ns_barrier" ::: "memory")

// ---------------- f32 -> bf16 convert ----------------
__global__ __launch_bounds__(256) void cvt_kernel(const float* __restrict__ src,
                                                  unsigned short* __restrict__ dst, int n) {
  int i = (blockIdx.x * 256 + threadIdx.x) * 4;
  if (i >= n) return;
  float4 v = *reinterpret_cast<const float4*>(src + i);
  ushort4 o;
  o.x = f2bf(v.x); o.y = f2bf(v.y); o.z = f2bf(v.z); o.w = f2bf(v.w);
  *reinterpret_cast<ushort4*>(dst + i) = o;
}

// 4 weight matrices in one launch
__global__ __launch_bounds__(256) void cvt_w_kernel(const float* __restrict__ wq,
                                                    const float* __restrict__ wk,
                                                    const float* __restrict__ wv,
                                                    const float* __restrict__ wp,
                                                    unsigned short* __restrict__ W3,
                                                    unsigned short* __restrict__ Wp) {
  const int g = blockIdx.x >> 10;
  const float* src = (g == 0) ? wq : (g == 1) ? wk : (g == 2) ? wv : wp;
  unsigned short* dst = (g < 3) ? (W3 + (long)g * 1048576) : Wp;
  int i = ((blockIdx.x & 1023) * 256 + threadIdx.x) * 4;
  float4 v = *reinterpret_cast<const float4*>(src + i);
  ushort4 o;
  o.x = f2bf(v.x); o.y = f2bf(v.y); o.z = f2bf(v.z); o.w = f2bf(v.w);
  *reinterpret_cast<ushort4*>(dst + i) = o;
}

// ================= 8-phase 256x256 bf16 GEMM (unchanged from R7) ==========
#define STAGE256(GP, GR0, KT, LOFF) do {                                          \
    const unsigned short* _s = (GP) + ((GR0) + wid * 8 + lr8) * 1024L             \
                               + (long)(KT) * 64 + skb * 8;                       \
    char* _d = (char*)lds + (LOFF) + wid * 1024;                                  \
    __builtin_amdgcn_global_load_lds((const __attribute__((address_space(1))) void*)_s,      \
        (__attribute__((address_space(3))) void*)_d, 16, 0, 0);                   \
    __builtin_amdgcn_global_load_lds((const __attribute__((address_space(1))) void*)(_s + 64 * 1024L), \
        (__attribute__((address_space(3))) void*)(_d + 8192), 16, 0, 0);          \
  } while (0)

#define PHASE256(AO, BO, MH, NH, STG) do {                                        \
    asm volatile("s_waitcnt vmcnt(6)" ::: "memory");                              \
    bf16x8 av[4][2], bv[2][2];                                                    \
    {                                                                             \
      const char* ab = (const char*)lds + (AO) + (MH) * 16384 + arow;             \
      const char* bb = (const char*)lds + (BO) + (NH) * 16384 + brow;             \
      _Pragma("unroll")                                                           \
      for (int j = 0; j < 4; ++j) {                                               \
        av[j][0] = *(const bf16x8*)(ab + j * 4096 + cb0);                         \
        av[j][1] = *(const bf16x8*)(ab + j * 4096 + cb1);                         \
      }                                                                           \
      _Pragma("unroll")                                                           \
      for (int j2 = 0; j2 < 2; ++j2) {                                            \
        bv[j2][0] = *(const bf16x8*)(bb + j2 * 8192 + cb0);                       \
        bv[j2][1] = *(const bf16x8*)(bb + j2 * 8192 + cb1);                       \
      }                                                                           \
    }                                                                             \
    STG;                                                                          \
    __builtin_amdgcn_s_barrier();                                                 \
    asm volatile("s_waitcnt lgkmcnt(0)" ::: "memory");                            \
    __builtin_amdgcn_sched_barrier(0);                                            \
    __builtin_amdgcn_s_setprio(1);                                                \
    _Pragma("unroll")                                                             \
    for (int j = 0; j < 4; ++j)                                                   \
      _Pragma("unroll")                                                           \
      for (int j2 = 0; j2 < 2; ++j2)                                              \
        acc[(MH) * 4 + j][(NH) * 2 + j2] = __builtin_amdgcn_mfma_f32_16x16x32_bf16( \
            av[j][0], bv[j2][0], acc[(MH) * 4 + j][(NH) * 2 + j2], 0, 0, 0);      \
    _Pragma("unroll")                                                             \
    for (int j = 0; j < 4; ++j)                                                   \
      _Pragma("unroll")                                                           \
      for (int j2 = 0; j2 < 2; ++j2)                                              \
        acc[(MH) * 4 + j][(NH) * 2 + j2] = __builtin_amdgcn_mfma_f32_16x16x32_bf16( \
            av[j][1], bv[j2][1], acc[(MH) * 4 + j][(NH) * 2 + j2], 0, 0, 0);      \
    __builtin_amdgcn_s_setprio(0);                                                \
    __builtin_amdgcn_s_barrier();                                                 \
  } while (0)

__global__ __launch_bounds__(512, 2) void gemm256_bt(
    const unsigned short* __restrict__ A,
    const unsigned short* __restrict__ Bw,
    unsigned short* __restrict__ C, int N) {
  __shared__ __align__(16) char lds[131072];
  enum { EA = 0, EB = 32768, OA = 65536, OB = 98304, HF = 16384 };
  const int tid = threadIdx.x;
  const int wid = tid >> 6, lane = tid & 63;
  const int wm = wid >> 2, wn = wid & 3;
  const int f = lane & 15, g = lane >> 4;
  const int lr8 = lane >> 3, lc = lane & 7;
  const int skb = lc ^ lr8;
  const long bM = (long)blockIdx.y * 256;
  const long bN = (long)blockIdx.x * 256;
  const int cb0 = ((0 + g) ^ (f & 7)) * 16;
  const int cb1 = ((4 + g) ^ (f & 7)) * 16;
  const int arow = (wm * 16 + f) * 128;
  const int brow = (wn * 16 + f) * 128;

  f32x4 acc[8][4] = {};

  STAGE256(A, bM, 0, EA);
  STAGE256(Bw, bN, 0, EB);
  STAGE256(A, bM + 128, 0, EA + HF);
  STAGE256(Bw, bN + 128, 0, EB + HF);
  STAGE256(Bw, bN, 1, OB);
  STAGE256(A, bM, 1, OA);
  asm volatile("s_waitcnt vmcnt(8)" ::: "memory");
  __builtin_amdgcn_s_barrier();

  for (int i = 0; i < 8; ++i) {
    const int todd = 2 * i + 1;
    int te = 2 * i + 2; if (te > 14) te = 14;
    int to = 2 * i + 3; if (to > 15) to = 15;
    PHASE256(EA, EB, 0, 0, STAGE256(A, bM + 128, todd, OA + HF));
    PHASE256(EA, EB, 1, 0, STAGE256(Bw, bN + 128, todd, OB + HF));
    PHASE256(EA, EB, 0, 1, STAGE256(Bw, bN, te, EB));
    PHASE256(EA, EB, 1, 1, STAGE256(A, bM, te, EA));
    PHASE256(OA, OB, 0, 0, STAGE256(A, bM + 128, te, EA + HF));
    PHASE256(OA, OB, 1, 0, STAGE256(Bw, bN + 128, te, EB + HF));
    PHASE256(OA, OB, 0, 1, STAGE256(Bw, bN, to, OB));
    PHASE256(OA, OB, 1, 1, STAGE256(A, bM, to, OA));
  }

#pragma unroll
  for (int mf = 0; mf < 8; ++mf) {
    long row = bM + (mf >> 2) * 128 + (mf & 3) * 32 + wm * 16 + g * 4;
#pragma unroll
    for (int nf = 0; nf < 4; ++nf) {
      long col = bN + (nf >> 1) * 128 + (nf & 1) * 64 + wn * 16 + f;
#pragma unroll
      for (int r = 0; r < 4; ++r)
        C[(row + r) * (long)N + col] = f2bf(acc[mf][nf][r]);
    }
  }
}

// ---------------- m97-style 128x128 GEMM (kept for gemm2) ----------------
template<int OUT_BF16>
__global__ __launch_bounds__(256) void gemm_bt(const unsigned short* __restrict__ A,
                                               const unsigned short* __restrict__ Bw,
                                               void* __restrict__ Cp,
                                               int M, int N, int K) {
  __shared__ __align__(16) unsigned short sA[128 * 32];
  __shared__ __align__(16) unsigned short sB[128 * 32];
  const int tid = threadIdx.x;
  const int wid = tid >> 6, lane = tid & 63;
  const int wm = wid >> 1, wn = wid & 1;
  const long blockM = (long)blockIdx.y * 128;
  const long blockN = (long)blockIdx.x * 128;

  f32x4 acc[4][4] = {};

  const int ar = lane >> 2;
  const int ac = (lane & 3) * 8;
  const unsigned short* Abase = A + (blockM + wid * 32 + ar) * (long)K + ac;
  const unsigned short* Bbase = Bw + (blockN + wid * 32 + ar) * (long)K + ac;
  char* sAb = (char*)sA + wid * 2048;
  char* sBb = (char*)sB + wid * 2048;

  for (int k0 = 0; k0 < K; k0 += 32) {
    __syncthreads();
    __builtin_amdgcn_global_load_lds((const __attribute__((address_space(1))) void*)(Abase + k0),
                                     (__attribute__((address_space(3))) void*)(sAb), 16, 0, 0);
    __builtin_amdgcn_global_load_lds((const __attribute__((address_space(1))) void*)(Abase + 16 * (long)K + k0),
                                     (__attribute__((address_space(3))) void*)(sAb + 1024), 16, 0, 0);
    __builtin_amdgcn_global_load_lds((const __attribute__((address_space(1))) void*)(Bbase + k0),
                                     (__attribute__((address_space(3))) void*)(sBb), 16, 0, 0);
    __builtin_amdgcn_global_load_lds((const __attribute__((address_space(1))) void*)(Bbase + 16 * (long)K + k0),
                                     (__attribute__((address_space(3))) void*)(sBb + 1024), 16, 0, 0);
    __syncthreads();

    const int koff = (lane >> 4) * 8;
    const int rA = wm * 64 + (lane & 15);
    const int rB = wn * 64 + (lane & 15);
    bf16x8 af[4], bfr[4];
#pragma unroll
    for (int m = 0; m < 4; ++m)
      af[m] = *reinterpret_cast<const bf16x8*>(&sA[(rA + m * 16) * 32 + koff]);
#pragma unroll
    for (int n = 0; n < 4; ++n)
      bfr[n] = *reinterpret_cast<const bf16x8*>(&sB[(rB + n * 16) * 32 + koff]);
#pragma unroll
    for (int m = 0; m < 4; ++m)
#pragma unroll
      for (int n = 0; n < 4; ++n)
        acc[m][n] = __builtin_amdgcn_mfma_f32_16x16x32_bf16(af[m], bfr[n], acc[m][n], 0, 0, 0);
  }

  const int cr = (lane >> 4) * 4;
  const int cc = lane & 15;
#pragma unroll
  for (int m = 0; m < 4; ++m) {
    long R = blockM + wm * 64 + m * 16 + cr;
#pragma unroll
    for (int n = 0; n < 4; ++n) {
      long Cc = blockN + wn * 64 + n * 16 + cc;
#pragma unroll
      for (int r = 0; r < 4; ++r) {
        if (OUT_BF16)
          ((unsigned short*)Cp)[(R + r) * (long)N + Cc] = f2bf(acc[m][n][r]);
        else
          ((float*)Cp)[(R + r) * (long)N + Cc] = acc[m][n][r];
      }
    }
  }
}

// ---------------- phase 1: per (bh, chunk) WY precompute (unchanged) ----------------
__global__ __launch_bounds__(256) void chunk_prep(
    unsigned short* __restrict__ qkv,
    const float* __restrict__ a_raw, const float* __restrict__ b_raw,
    unsigned short* __restrict__ Ubuf, unsigned short* __restrict__ Wbuf,
    unsigned short* __restrict__ SLbuf) {
  __shared__ __align__(16) unsigned short sK[64 * 64];
  __shared__ __align__(16) unsigned short sQ[64 * 64];
  __shared__ __align__(16) unsigned short sV[64 * 64];
  __shared__ float sA[64 * 64];

  const int blk = blockIdx.x;           // bh*32 + c
  const int bh = blk >> 5, c = blk & 31;
  const int b = bh >> 4, h = bh & 15;
  const int tid = threadIdx.x;
  const int wid = tid >> 6, lane = tid & 63;

  const float alpha = 0.5f / (1.f + __expf(-a_raw[h]));
  const float beta  = 0.5f / (1.f + __expf(-b_raw[h]));

  {
    const int row = tid >> 2, cg = tid & 3;
    unsigned short* gp = qkv + (long)(b * 2048 + c * 64 + row) * 3072 + h * 64 + cg * 16;
    bf16x8 q0 = *(const bf16x8*)(gp);
    bf16x8 q1 = *(const bf16x8*)(gp + 8);
    bf16x8 k0 = *(const bf16x8*)(gp + 1024);
    bf16x8 k1 = *(const bf16x8*)(gp + 1024 + 8);
    bf16x8 v0 = *(const bf16x8*)(gp + 2048);
    bf16x8 v1 = *(const bf16x8*)(gp + 2048 + 8);
    float kf[16];
    float ss = 0.f;
#pragma unroll
    for (int i = 0; i < 8; ++i) { kf[i] = bf2f((unsigned short)k0[i]); ss += kf[i] * kf[i]; }
#pragma unroll
    for (int i = 0; i < 8; ++i) { kf[8 + i] = bf2f((unsigned short)k1[i]); ss += kf[8 + i] * kf[8 + i]; }
    ss += __shfl_xor(ss, 1);
    ss += __shfl_xor(ss, 2);
    const float inv = 1.f / fmaxf(sqrtf(ss), 1e-12f);
    bf16x8 n0, n1;
#pragma unroll
    for (int i = 0; i < 8; ++i) { n0[i] = (short)f2bf(kf[i] * inv); n1[i] = (short)f2bf(kf[8 + i] * inv); }
    *(bf16x8*)((char*)sK + swz128(row, cg * 32)) = n0;
    *(bf16x8*)((char*)sK + swz128(row, cg * 32 + 16)) = n1;
    *(bf16x8*)(gp + 1024) = n0;
    *(bf16x8*)(gp + 1024 + 8) = n1;
    *(bf16x8*)((char*)sQ + swz128(row, cg * 32)) = q0;
    *(bf16x8*)((char*)sQ + swz128(row, cg * 32 + 16)) = q1;
    *(bf16x8*)((char*)sV + row * 128 + cg * 32) = v0;
    *(bf16x8*)((char*)sV + row * 128 + cg * 32 + 16) = v1;
  }
  __syncthreads();

  const int rfrag = lane & 15, koff = (lane >> 4) * 8, crow = (lane >> 4) * 4;
  const int w2 = wid & 1;
  if (wid < 2) {
#pragma unroll
    for (int mt = 0; mt < 2; ++mt) {
      const int m = w2 * 2 + mt;
      const int ra = 16 * m + rfrag;
      f32x4 acc[4] = {};
#pragma unroll
      for (int ks = 0; ks < 2; ++ks) {
        bf16x8 af = *(const bf16x8*)((const char*)sK + swz128(ra, ks * 64 + koff * 2));
#pragma unroll
        for (int n = 0; n < 4; ++n) {
          bf16x8 bf = *(const bf16x8*)((const char*)sK + swz128(16 * n + rfrag, ks * 64 + koff * 2));
          acc[n] = __builtin_amdgcn_mfma_f32_16x16x32_bf16(af, bf, acc[n], 0, 0, 0);
        }
      }
#pragma unroll
      for (int n = 0; n < 4; ++n)
#pragma unroll
        for (int r = 0; r < 4; ++r)
          sA[(16 * m + crow + r) * 64 + 16 * n + rfrag] = acc[n][r];
    }
  } else {
#pragma unroll
    for (int mt = 0; mt < 2; ++mt) {
      const int m = w2 * 2 + mt;
      const int ra = 16 * m + rfrag;
      f32x4 acc[4] = {};
#pragma unroll
      for (int ks = 0; ks < 2; ++ks) {
        bf16x8 af = *(const bf16x8*)((const char*)sQ + swz128(ra, ks * 64 + koff * 2));
#pragma unroll
        for (int n = 0; n < 4; ++n) {
          bf16x8 bf = *(const bf16x8*)((const char*)sK + swz128(16 * n + rfrag, ks * 64 + koff * 2));
          acc[n] = __builtin_amdgcn_mfma_f32_16x16x32_bf16(af, bf, acc[n], 0, 0, 0);
        }
      }
#pragma unroll
      for (int n = 0; n < 4; ++n)
#pragma unroll
        for (int r = 0; r < 4; ++r) {
          int t = 16 * m + crow + r, j = 16 * n + rfrag;
          SLbuf[(long)blk * 4096 + t * 64 + j] = (j < t) ? f2bf(acc[n][r]) : (unsigned short)0;
        }
    }
  }
  __syncthreads();

  if (wid < 2) {
    const int d = lane;
    float x[64];
#pragma unroll
    for (int t = 0; t < 64; ++t) {
      float rhs;
      if (wid == 0) rhs = beta * bf2f(sV[t * 64 + d]);
      else          rhs = alpha * bf2f(*(const unsigned short*)((const char*)sK + swz128(t, 2 * d)));
      float s = 0.f;
#pragma unroll
      for (int j = 0; j < t; ++j) s = fmaf(sA[t * 64 + j], x[j], s);
      x[t] = rhs - alpha * s;
    }
    unsigned short* ob = (wid == 0 ? Ubuf : Wbuf) + (long)blk * 4096 + d;
#pragma unroll
    for (int t = 0; t < 64; ++t) ob[t * 64] = f2bf(x[t]);
  }
}

// ---------------- phase 2: wave-private chunk recurrence ----------------
// Block = one (b,h); wave wid owns d-quarter dq=wid end-to-end.
// Shared double-buffered tiles Q/W/SL/KT/U (1 LDS_BARRIER per chunk);
// S<->G transpose hops via per-wave private LDS (no barriers, compiler lgkm).
// Per wave per chunk: 32 MFMA; G = U - W*S^T; Y = Q*S^T + SL*G; S += G^T*K.
__global__ __launch_bounds__(256) void chunk_scan(
    const unsigned short* __restrict__ qkv,
    const unsigned short* __restrict__ Ubuf, const unsigned short* __restrict__ Wbuf,
    const unsigned short* __restrict__ SLbuf,
    const float* __restrict__ state_in, unsigned short* __restrict__ ybuf,
    float* __restrict__ state_out) {
  __shared__ __align__(16) char lds[98304];
  // buf k at k*40960: Q +0, W +8192, SL +16384, KT +24576, U +32768 (8KB each)
  // private: GT at 81920 + wid*2048, S at 90112 + wid*2048 (16 rows x 128B)
  const int bh = blockIdx.x;
  const int b = bh >> 4, h = bh & 15;
  const int tid = threadIdx.x, wid = tid >> 6, lane = tid & 63;
  const int f = lane & 15, koff = (lane >> 4) * 8, crow = (lane >> 4) * 4;
  const int row = tid >> 2, cg = tid & 3;
  const int dq = wid;

  char* gt = lds + 81920 + wid * 2048;
  char* ss = lds + 90112 + wid * 2048;

  const unsigned short* gpb = qkv + (long)(b * 2048 + row) * 3072 + h * 64 + cg * 16;
  const long tbb = ((long)(bh * 32) * 64 + row) * 64 + cg * 16;

  bf16x8 qv0, qv1, kv0, kv1, wv0, wv1, sl0, sl1, uv0, uv1;
#define LOADREGS(CN) do {                                                     \
    const unsigned short* gp = gpb + (long)(CN) * 64 * 3072;                  \
    const long tb = tbb + (long)(CN) * 4096;                                  \
    qv0 = *(const bf16x8*)gp;            qv1 = *(const bf16x8*)(gp + 8);      \
    kv0 = *(const bf16x8*)(gp + 1024);   kv1 = *(const bf16x8*)(gp + 1032);   \
    wv0 = *(const bf16x8*)(Wbuf + tb);   wv1 = *(const bf16x8*)(Wbuf + tb + 8); \
    sl0 = *(const bf16x8*)(SLbuf + tb);  sl1 = *(const bf16x8*)(SLbuf + tb + 8); \
    uv0 = *(const bf16x8*)(Ubuf + tb);   uv1 = *(const bf16x8*)(Ubuf + tb + 8); \
  } while (0)

#define WRITE_TILES(BUF) do {                                                 \
    char* bp = lds + (BUF) * 40960;                                           \
    *(bf16x8*)(bp + swz128(row, cg * 32)) = qv0;                              \
    *(bf16x8*)(bp + swz128(row, cg * 32 + 16)) = qv1;                         \
    *(bf16x8*)(bp + 8192 + swz128(row, cg * 32)) = wv0;                       \
    *(bf16x8*)(bp + 8192 + swz128(row, cg * 32 + 16)) = wv1;                  \
    *(bf16x8*)(bp + 16384 + swz128(row, cg * 32)) = sl0;                      \
    *(bf16x8*)(bp + 16384 + swz128(row, cg * 32 + 16)) = sl1;                 \
    _Pragma("unroll")                                                         \
    for (int i = 0; i < 8; ++i) {                                             \
      *(unsigned short*)(bp + 24576 + swz128(cg * 16 + i, 2 * row)) = (unsigned short)kv0[i]; \
      *(unsigned short*)(bp + 24576 + swz128(cg * 16 + 8 + i, 2 * row)) = (unsigned short)kv1[i]; \
    }                                                                         \
    *(bf16x8*)(bp + 32768 + swz128(row, cg * 32)) = uv0;                      \
    *(bf16x8*)(bp + 32768 + swz128(row, cg * 32 + 16)) = uv1;                 \
  } while (0)

  // S quarter init: rows [dq*16, dq*16+16), all 64 e-cols; acc D-layout col=e.
  f32x4 sacc[4];
#pragma unroll
  for (int nn = 0; nn < 4; ++nn)
#pragma unroll
    for (int r = 0; r < 4; ++r)
      sacc[nn][r] = state_in[(long)bh * 4096 + (dq * 16 + crow + r) * 64 + nn * 16 + f];
#pragma unroll
  for (int nn = 0; nn < 4; ++nn)
#pragma unroll
    for (int r = 0; r < 4; ++r)
      *(unsigned short*)(ss + swz128(crow + r, 2 * (nn * 16 + f))) = f2bf(sacc[nn][r]);

  // prologue: stage chunk 0 into buf0, prefetch chunk 1
  LOADREGS(0);
  WRITE_TILES(0);
  LOADREGS(1);
  LDS_BARRIER();

  for (int c = 0; c < NC_; ++c) {
    const int cur = c & 1;
    // stage chunk c+1 into the other buffer (last read at chunk c-1, fenced)
    if (c + 1 < NC_) WRITE_TILES(cur ^ 1);
    {
      int cn = c + 2; if (cn > NC_ - 1) cn = NC_ - 1;
      LOADREGS(cn);
    }

    const char* bp = lds + cur * 40960;
    // bS frags (private S transpose, written end of prev chunk)
    bf16x8 bs0 = *(const bf16x8*)(ss + swz128(f, koff * 2));
    bf16x8 bs1 = *(const bf16x8*)(ss + swz128(f, 64 + koff * 2));

    // P = W * S^T  (4 m-tiles x 2 ks)
    f32x4 p[4];
#pragma unroll
    for (int m = 0; m < 4; ++m) {
      bf16x8 a0 = *(const bf16x8*)(bp + 8192 + swz128(m * 16 + f, koff * 2));
      bf16x8 a1 = *(const bf16x8*)(bp + 8192 + swz128(m * 16 + f, 64 + koff * 2));
      f32x4 z = {};
      z = __builtin_amdgcn_mfma_f32_16x16x32_bf16(a0, bs0, z, 0, 0, 0);
      p[m] = __builtin_amdgcn_mfma_f32_16x16x32_bf16(a1, bs1, z, 0, 0, 0);
    }
    // G = U - P -> private GT [dl][t]
#pragma unroll
    for (int m = 0; m < 4; ++m)
#pragma unroll
      for (int r = 0; r < 4; ++r) {
        int t = m * 16 + crow + r;
        float u = bf2f(*(const unsigned short*)(bp + 32768 + swz128(t, 2 * (dq * 16 + f))));
        *(unsigned short*)(gt + swz128(f, 2 * t)) = f2bf(u - p[m][r]);
      }
    // Yq = Q * S^T (independent of G; hides GT write latency)
    f32x4 yac[4];
#pragma unroll
    for (int m = 0; m < 4; ++m) {
      bf16x8 a0 = *(const bf16x8*)(bp + swz128(m * 16 + f, koff * 2));
      bf16x8 a1 = *(const bf16x8*)(bp + swz128(m * 16 + f, 64 + koff * 2));
      f32x4 z = {};
      z = __builtin_amdgcn_mfma_f32_16x16x32_bf16(a0, bs0, z, 0, 0, 0);
      yac[m] = __builtin_amdgcn_mfma_f32_16x16x32_bf16(a1, bs1, z, 0, 0, 0);
    }
    // G frags (A-frag for S-update == B-frag for SL*G: same bytes)
    bf16x8 g0 = *(const bf16x8*)(gt + swz128(f, koff * 2));
    bf16x8 g1 = *(const bf16x8*)(gt + swz128(f, 64 + koff * 2));
    // Y += SL * G
#pragma unroll
    for (int m = 0; m < 4; ++m) {
      bf16x8 a0 = *(const bf16x8*)(bp + 16384 + swz128(m * 16 + f, koff * 2));
      bf16x8 a1 = *(const bf16x8*)(bp + 16384 + swz128(m * 16 + f, 64 + koff * 2));
      yac[m] = __builtin_amdgcn_mfma_f32_16x16x32_bf16(a0, g0, yac[m], 0, 0, 0);
      yac[m] = __builtin_amdgcn_mfma_f32_16x16x32_bf16(a1, g1, yac[m], 0, 0, 0);
    }
    // S += G^T * K  (4 n-tiles over e)
#pragma unroll
    for (int nn = 0; nn < 4; ++nn) {
      bf16x8 b0 = *(const bf16x8*)(bp + 24576 + swz128(nn * 16 + f, koff * 2));
      bf16x8 b1 = *(const bf16x8*)(bp + 24576 + swz128(nn * 16 + f, 64 + koff * 2));
      sacc[nn] = __builtin_amdgcn_mfma_f32_16x16x32_bf16(g0, b0, sacc[nn], 0, 0, 0);
      sacc[nn] = __builtin_amdgcn_mfma_f32_16x16x32_bf16(g1, b1, sacc[nn], 0, 0, 0);
    }
    // y stores (fire-and-forget)
#pragma unroll
    for (int m = 0; m < 4; ++m)
#pragma unroll
      for (int r = 0; r < 4; ++r) {
        int t = m * 16 + crow + r;
        ybuf[(long)(b * 2048 + c * 64 + t) * 1024 + h * 64 + dq * 16 + f] = f2bf(yac[m][r]);
      }
    // refresh private bf16 S for next chunk's stage A
#pragma unroll
    for (int nn = 0; nn < 4; ++nn)
#pragma unroll
      for (int r = 0; r < 4; ++r)
        *(unsigned short*)(ss + swz128(crow + r, 2 * (nn * 16 + f))) = f2bf(sacc[nn][r]);

    LDS_BARRIER();   // tiles for c+1 staged; all reads of buf cur complete
  }

#pragma unroll
  for (int nn = 0; nn < 4; ++nn)
#pragma unroll
    for (int r = 0; r < 4; ++r)
      state_out[(long)bh * 4096 + (dq * 16 + crow + r) * 64 + nn * 16 + f] = sacc[nn][r];
#undef LOADREGS
#undef WRITE_TILES
}

// ---------------- launch ----------------
extern "C" void kernel_launch(void* const* d_in, const int* in_sizes, int n_in,
                              void* d_out, int out_size, void* d_ws, size_t ws_size,
                              hipStream_t stream) {
  (void)in_sizes; (void)n_in; (void)out_size; (void)ws_size;
  const float* x     = (const float*)d_in[0];
  const float* Wq    = (const float*)d_in[1];
  const float* Wk    = (const float*)d_in[2];
  const float* Wv    = (const float*)d_in[3];
  const float* Wproj = (const float*)d_in[4];
  const float* a_raw = (const float*)d_in[5];
  const float* b_raw = (const float*)d_in[6];
  const float* state = (const float*)d_in[7];

  char* ws = (char*)d_ws;
  unsigned short* xbf = (unsigned short*)ws;                    // 16MB; reused as y
  unsigned short* W3  = (unsigned short*)(ws + (16l << 20));    // 6MB [Wq;Wk;Wv]
  unsigned short* Wp  = (unsigned short*)(ws + (22l << 20));    // 2MB
  unsigned short* qkv = (unsigned short*)(ws + (24l << 20));    // 48MB
  unsigned short* Ub  = (unsigned short*)(ws + (72l << 20));    // 16MB
  unsigned short* Wb  = (unsigned short*)(ws + (88l << 20));    // 16MB
  unsigned short* SLb = (unsigned short*)(ws + (104l << 20));   // 16MB -> 120MB total
  float* out = (float*)d_out;
  float* state_out = out + (long)B_ * T_ * C_;

  cvt_kernel<<<dim3(8192), dim3(256), 0, stream>>>(x, xbf, 8388608);
  cvt_w_kernel<<<dim3(4096), dim3(256), 0, stream>>>(Wq, Wk, Wv, Wproj, W3, Wp);

  gemm256_bt<<<dim3(3072 / 256, 8192 / 256), dim3(512), 0, stream>>>(xbf, W3, qkv, 3072);

  chunk_prep<<<dim3(2048), dim3(256), 0, stream>>>(qkv, a_raw, b_raw, Ub, Wb, SLb);
  chunk_scan<<<dim3(64), dim3(256), 0, stream>>>(qkv, Ub, Wb, SLb, state, xbf, state_out);

  gemm_bt<0><<<dim3(1024 / 128, 8192 / 128), dim3(256), 0, stream>>>(xbf, Wp, (void*)out, 8192, 1024, 1024);
}

// Round 9
// 206.878 us; speedup vs baseline: 1.0794x; 1.0794x over previous
//
#include <hip/hip_runtime.h>
#include <hip/hip_bf16.h>
#include <cstdint>

#define B_ 4
#define T_ 2048
#define C_ 1024
#define H_ 16
#define D_ 64
#define NC_ 32   // chunks
#define L_ 64    // chunk length

typedef __attribute__((ext_vector_type(8))) short bf16x8;
typedef __attribute__((ext_vector_type(4))) float f32x4;

static __device__ __forceinline__ unsigned short f2bf(float f) {
  unsigned u = __float_as_uint(f);
  u += 0x7fff + ((u >> 16) & 1);   // round-to-nearest-even
  return (unsigned short)(u >> 16);
}
static __device__ __forceinline__ float bf2f(unsigned short b) {
  return __uint_as_float(((unsigned)b) << 16);
}
// XOR swizzle for 128B-stride LDS rows (T2): keeps 16B alignment, <=2-way conflicts
static __device__ __forceinline__ int swz128(int row, int byte) {
  return row * 128 + (byte ^ ((row & 7) << 4));
}

// Barrier that does NOT drain vmcnt (T4): LDS edges fenced via lgkmcnt(0).
#define LDS_BARRIER() asm volatile("s_waitcnt lgkmcnt(0)\ns_barrier" ::: "memory")

// ---------------- f32 -> bf16 convert ----------------
__global__ __launch_bounds__(256) void cvt_kernel(const float* __restrict__ src,
                                                  unsigned short* __restrict__ dst, int n) {
  int i = (blockIdx.x * 256 + threadIdx.x) * 4;
  if (i >= n) return;
  float4 v = *reinterpret_cast<const float4*>(src + i);
  ushort4 o;
  o.x = f2bf(v.x); o.y = f2bf(v.y); o.z = f2bf(v.z); o.w = f2bf(v.w);
  *reinterpret_cast<ushort4*>(dst + i) = o;
}

// 4 weight matrices in one launch
__global__ __launch_bounds__(256) void cvt_w_kernel(const float* __restrict__ wq,
                                                    const float* __restrict__ wk,
                                                    const float* __restrict__ wv,
                                                    const float* __restrict__ wp,
                                                    unsigned short* __restrict__ W3,
                                                    unsigned short* __restrict__ Wp) {
  const int g = blockIdx.x >> 10;
  const float* src = (g == 0) ? wq : (g == 1) ? wk : (g == 2) ? wv : wp;
  unsigned short* dst = (g < 3) ? (W3 + (long)g * 1048576) : Wp;
  int i = ((blockIdx.x & 1023) * 256 + threadIdx.x) * 4;
  float4 v = *reinterpret_cast<const float4*>(src + i);
  ushort4 o;
  o.x = f2bf(v.x); o.y = f2bf(v.y); o.z = f2bf(v.z); o.w = f2bf(v.w);
  *reinterpret_cast<ushort4*>(dst + i) = o;
}

// ================= 8-phase 256x256 bf16 GEMM (T1+T2+T3+T4+T5) ==========
#define STAGE256(GP, GR0, KT, LOFF) do {                                          \
    const unsigned short* _s = (GP) + ((GR0) + wid * 8 + lr8) * 1024L             \
                               + (long)(KT) * 64 + skb * 8;                       \
    char* _d = (char*)lds + (LOFF) + wid * 1024;                                  \
    __builtin_amdgcn_global_load_lds((const __attribute__((address_space(1))) void*)_s,      \
        (__attribute__((address_space(3))) void*)_d, 16, 0, 0);                   \
    __builtin_amdgcn_global_load_lds((const __attribute__((address_space(1))) void*)(_s + 64 * 1024L), \
        (__attribute__((address_space(3))) void*)(_d + 8192), 16, 0, 0);          \
  } while (0)

#define PHASE256(AO, BO, MH, NH, STG) do {                                        \
    asm volatile("s_waitcnt vmcnt(6)" ::: "memory");                              \
    bf16x8 av[4][2], bv[2][2];                                                    \
    {                                                                             \
      const char* ab = (const char*)lds + (AO) + (MH) * 16384 + arow;             \
      const char* bb = (const char*)lds + (BO) + (NH) * 16384 + brow;             \
      _Pragma("unroll")                                                           \
      for (int j = 0; j < 4; ++j) {                                               \
        av[j][0] = *(const bf16x8*)(ab + j * 4096 + cb0);                         \
        av[j][1] = *(const bf16x8*)(ab + j * 4096 + cb1);                         \
      }                                                                           \
      _Pragma("unroll")                                                           \
      for (int j2 = 0; j2 < 2; ++j2) {                                            \
        bv[j2][0] = *(const bf16x8*)(bb + j2 * 8192 + cb0);                       \
        bv[j2][1] = *(const bf16x8*)(bb + j2 * 8192 + cb1);                       \
      }                                                                           \
    }                                                                             \
    STG;                                                                          \
    __builtin_amdgcn_s_barrier();                                                 \
    asm volatile("s_waitcnt lgkmcnt(0)" ::: "memory");                            \
    __builtin_amdgcn_sched_barrier(0);                                            \
    __builtin_amdgcn_s_setprio(1);                                                \
    _Pragma("unroll")                                                             \
    for (int j = 0; j < 4; ++j)                                                   \
      _Pragma("unroll")                                                           \
      for (int j2 = 0; j2 < 2; ++j2)                                              \
        acc[(MH) * 4 + j][(NH) * 2 + j2] = __builtin_amdgcn_mfma_f32_16x16x32_bf16( \
            av[j][0], bv[j2][0], acc[(MH) * 4 + j][(NH) * 2 + j2], 0, 0, 0);      \
    _Pragma("unroll")                                                             \
    for (int j = 0; j < 4; ++j)                                                   \
      _Pragma("unroll")                                                           \
      for (int j2 = 0; j2 < 2; ++j2)                                              \
        acc[(MH) * 4 + j][(NH) * 2 + j2] = __builtin_amdgcn_mfma_f32_16x16x32_bf16( \
            av[j][1], bv[j2][1], acc[(MH) * 4 + j][(NH) * 2 + j2], 0, 0, 0);      \
    __builtin_amdgcn_s_setprio(0);                                                \
    __builtin_amdgcn_s_barrier();                                                 \
  } while (0)

__global__ __launch_bounds__(512, 2) void gemm256_bt(
    const unsigned short* __restrict__ A,
    const unsigned short* __restrict__ Bw,
    unsigned short* __restrict__ C, int N) {
  __shared__ __align__(16) char lds[131072];
  enum { EA = 0, EB = 32768, OA = 65536, OB = 98304, HF = 16384 };
  const int tid = threadIdx.x;
  const int wid = tid >> 6, lane = tid & 63;
  const int wm = wid >> 2, wn = wid & 3;
  const int f = lane & 15, g = lane >> 4;
  const int lr8 = lane >> 3, lc = lane & 7;
  const int skb = lc ^ lr8;
  // T1: bijective XCD-chunked swizzle (nwg % 8 == 0 for both call sites)
  const int bid = blockIdx.y * gridDim.x + blockIdx.x;
  const int cpx = (gridDim.x * gridDim.y) >> 3;
  const int sw = (bid & 7) * cpx + (bid >> 3);
  const long bM = (long)(sw / gridDim.x) * 256;
  const long bN = (long)(sw % gridDim.x) * 256;
  const int cb0 = ((0 + g) ^ (f & 7)) * 16;
  const int cb1 = ((4 + g) ^ (f & 7)) * 16;
  const int arow = (wm * 16 + f) * 128;
  const int brow = (wn * 16 + f) * 128;

  f32x4 acc[8][4] = {};

  STAGE256(A, bM, 0, EA);
  STAGE256(Bw, bN, 0, EB);
  STAGE256(A, bM + 128, 0, EA + HF);
  STAGE256(Bw, bN + 128, 0, EB + HF);
  STAGE256(Bw, bN, 1, OB);
  STAGE256(A, bM, 1, OA);
  asm volatile("s_waitcnt vmcnt(8)" ::: "memory");
  __builtin_amdgcn_s_barrier();

  for (int i = 0; i < 8; ++i) {
    const int todd = 2 * i + 1;
    int te = 2 * i + 2; if (te > 14) te = 14;
    int to = 2 * i + 3; if (to > 15) to = 15;
    PHASE256(EA, EB, 0, 0, STAGE256(A, bM + 128, todd, OA + HF));
    PHASE256(EA, EB, 1, 0, STAGE256(Bw, bN + 128, todd, OB + HF));
    PHASE256(EA, EB, 0, 1, STAGE256(Bw, bN, te, EB));
    PHASE256(EA, EB, 1, 1, STAGE256(A, bM, te, EA));
    PHASE256(OA, OB, 0, 0, STAGE256(A, bM + 128, te, EA + HF));
    PHASE256(OA, OB, 1, 0, STAGE256(Bw, bN + 128, te, EB + HF));
    PHASE256(OA, OB, 0, 1, STAGE256(Bw, bN, to, OB));
    PHASE256(OA, OB, 1, 1, STAGE256(A, bM, to, OA));
  }

#pragma unroll
  for (int mf = 0; mf < 8; ++mf) {
    long row = bM + (mf >> 2) * 128 + (mf & 3) * 32 + wm * 16 + g * 4;
#pragma unroll
    for (int nf = 0; nf < 4; ++nf) {
      long col = bN + (nf >> 1) * 128 + (nf & 1) * 64 + wn * 16 + f;
#pragma unroll
      for (int r = 0; r < 4; ++r)
        C[(row + r) * (long)N + col] = f2bf(acc[mf][nf][r]);
    }
  }
}

// ---------------- m97-style 128x128 GEMM (gemm2) ----------------
template<int OUT_BF16>
__global__ __launch_bounds__(256) void gemm_bt(const unsigned short* __restrict__ A,
                                               const unsigned short* __restrict__ Bw,
                                               void* __restrict__ Cp,
                                               int M, int N, int K) {
  __shared__ __align__(16) unsigned short sA[128 * 32];
  __shared__ __align__(16) unsigned short sB[128 * 32];
  const int tid = threadIdx.x;
  const int wid = tid >> 6, lane = tid & 63;
  const int wm = wid >> 1, wn = wid & 1;
  // T1 swizzle (512 blocks % 8 == 0)
  const int bid = blockIdx.y * gridDim.x + blockIdx.x;
  const int cpx = (gridDim.x * gridDim.y) >> 3;
  const int sw = (bid & 7) * cpx + (bid >> 3);
  const long blockM = (long)(sw / gridDim.x) * 128;
  const long blockN = (long)(sw % gridDim.x) * 128;

  f32x4 acc[4][4] = {};

  const int ar = lane >> 2;
  const int ac = (lane & 3) * 8;
  const unsigned short* Abase = A + (blockM + wid * 32 + ar) * (long)K + ac;
  const unsigned short* Bbase = Bw + (blockN + wid * 32 + ar) * (long)K + ac;
  char* sAb = (char*)sA + wid * 2048;
  char* sBb = (char*)sB + wid * 2048;

  for (int k0 = 0; k0 < K; k0 += 32) {
    __syncthreads();
    __builtin_amdgcn_global_load_lds((const __attribute__((address_space(1))) void*)(Abase + k0),
                                     (__attribute__((address_space(3))) void*)(sAb), 16, 0, 0);
    __builtin_amdgcn_global_load_lds((const __attribute__((address_space(1))) void*)(Abase + 16 * (long)K + k0),
                                     (__attribute__((address_space(3))) void*)(sAb + 1024), 16, 0, 0);
    __builtin_amdgcn_global_load_lds((const __attribute__((address_space(1))) void*)(Bbase + k0),
                                     (__attribute__((address_space(3))) void*)(sBb), 16, 0, 0);
    __builtin_amdgcn_global_load_lds((const __attribute__((address_space(1))) void*)(Bbase + 16 * (long)K + k0),
                                     (__attribute__((address_space(3))) void*)(sBb + 1024), 16, 0, 0);
    __syncthreads();

    const int koff = (lane >> 4) * 8;
    const int rA = wm * 64 + (lane & 15);
    const int rB = wn * 64 + (lane & 15);
    bf16x8 af[4], bfr[4];
#pragma unroll
    for (int m = 0; m < 4; ++m)
      af[m] = *reinterpret_cast<const bf16x8*>(&sA[(rA + m * 16) * 32 + koff]);
#pragma unroll
    for (int n = 0; n < 4; ++n)
      bfr[n] = *reinterpret_cast<const bf16x8*>(&sB[(rB + n * 16) * 32 + koff]);
#pragma unroll
    for (int m = 0; m < 4; ++m)
#pragma unroll
      for (int n = 0; n < 4; ++n)
        acc[m][n] = __builtin_amdgcn_mfma_f32_16x16x32_bf16(af[m], bfr[n], acc[m][n], 0, 0, 0);
  }

  const int cr = (lane >> 4) * 4;
  const int cc = lane & 15;
#pragma unroll
  for (int m = 0; m < 4; ++m) {
    long R = blockM + wm * 64 + m * 16 + cr;
#pragma unroll
    for (int n = 0; n < 4; ++n) {
      long Cc = blockN + wn * 64 + n * 16 + cc;
#pragma unroll
      for (int r = 0; r < 4; ++r) {
        if (OUT_BF16)
          ((unsigned short*)Cp)[(R + r) * (long)N + Cc] = f2bf(acc[m][n][r]);
        else
          ((float*)Cp)[(R + r) * (long)N + Cc] = acc[m][n][r];
      }
    }
  }
}

// ---------------- phase 1: per (bh, chunk) WY precompute ----------------
__global__ __launch_bounds__(256) void chunk_prep(
    unsigned short* __restrict__ qkv,
    const float* __restrict__ a_raw, const float* __restrict__ b_raw,
    unsigned short* __restrict__ Ubuf, unsigned short* __restrict__ Wbuf,
    unsigned short* __restrict__ SLbuf) {
  __shared__ __align__(16) unsigned short sK[64 * 64];
  __shared__ __align__(16) unsigned short sQ[64 * 64];
  __shared__ __align__(16) unsigned short sV[64 * 64];
  __shared__ float sA[64 * 64];

  const int blk = blockIdx.x;           // bh*32 + c
  const int bh = blk >> 5, c = blk & 31;
  const int b = bh >> 4, h = bh & 15;
  const int tid = threadIdx.x;
  const int wid = tid >> 6, lane = tid & 63;

  const float alpha = 0.5f / (1.f + __expf(-a_raw[h]));
  const float beta  = 0.5f / (1.f + __expf(-b_raw[h]));

  {
    const int row = tid >> 2, cg = tid & 3;
    unsigned short* gp = qkv + (long)(b * 2048 + c * 64 + row) * 3072 + h * 64 + cg * 16;
    bf16x8 q0 = *(const bf16x8*)(gp);
    bf16x8 q1 = *(const bf16x8*)(gp + 8);
    bf16x8 k0 = *(const bf16x8*)(gp + 1024);
    bf16x8 k1 = *(const bf16x8*)(gp + 1024 + 8);
    bf16x8 v0 = *(const bf16x8*)(gp + 2048);
    bf16x8 v1 = *(const bf16x8*)(gp + 2048 + 8);
    float kf[16];
    float ss = 0.f;
#pragma unroll
    for (int i = 0; i < 8; ++i) { kf[i] = bf2f((unsigned short)k0[i]); ss += kf[i] * kf[i]; }
#pragma unroll
    for (int i = 0; i < 8; ++i) { kf[8 + i] = bf2f((unsigned short)k1[i]); ss += kf[8 + i] * kf[8 + i]; }
    ss += __shfl_xor(ss, 1);
    ss += __shfl_xor(ss, 2);
    const float inv = 1.f / fmaxf(sqrtf(ss), 1e-12f);
    bf16x8 n0, n1;
#pragma unroll
    for (int i = 0; i < 8; ++i) { n0[i] = (short)f2bf(kf[i] * inv); n1[i] = (short)f2bf(kf[8 + i] * inv); }
    *(bf16x8*)((char*)sK + swz128(row, cg * 32)) = n0;
    *(bf16x8*)((char*)sK + swz128(row, cg * 32 + 16)) = n1;
    *(bf16x8*)(gp + 1024) = n0;
    *(bf16x8*)(gp + 1024 + 8) = n1;
    *(bf16x8*)((char*)sQ + swz128(row, cg * 32)) = q0;
    *(bf16x8*)((char*)sQ + swz128(row, cg * 32 + 16)) = q1;
    *(bf16x8*)((char*)sV + row * 128 + cg * 32) = v0;
    *(bf16x8*)((char*)sV + row * 128 + cg * 32 + 16) = v1;
  }
  __syncthreads();

  const int rfrag = lane & 15, koff = (lane >> 4) * 8, crow = (lane >> 4) * 4;
  const int w2 = wid & 1;
  if (wid < 2) {
#pragma unroll
    for (int mt = 0; mt < 2; ++mt) {
      const int m = w2 * 2 + mt;
      const int ra = 16 * m + rfrag;
      f32x4 acc[4] = {};
#pragma unroll
      for (int ks = 0; ks < 2; ++ks) {
        bf16x8 af = *(const bf16x8*)((const char*)sK + swz128(ra, ks * 64 + koff * 2));
#pragma unroll
        for (int n = 0; n < 4; ++n) {
          bf16x8 bf = *(const bf16x8*)((const char*)sK + swz128(16 * n + rfrag, ks * 64 + koff * 2));
          acc[n] = __builtin_amdgcn_mfma_f32_16x16x32_bf16(af, bf, acc[n], 0, 0, 0);
        }
      }
#pragma unroll
      for (int n = 0; n < 4; ++n)
#pragma unroll
        for (int r = 0; r < 4; ++r)
          sA[(16 * m + crow + r) * 64 + 16 * n + rfrag] = acc[n][r];
    }
  } else {
#pragma unroll
    for (int mt = 0; mt < 2; ++mt) {
      const int m = w2 * 2 + mt;
      const int ra = 16 * m + rfrag;
      f32x4 acc[4] = {};
#pragma unroll
      for (int ks = 0; ks < 2; ++ks) {
        bf16x8 af = *(const bf16x8*)((const char*)sQ + swz128(ra, ks * 64 + koff * 2));
#pragma unroll
        for (int n = 0; n < 4; ++n) {
          bf16x8 bf = *(const bf16x8*)((const char*)sK + swz128(16 * n + rfrag, ks * 64 + koff * 2));
          acc[n] = __builtin_amdgcn_mfma_f32_16x16x32_bf16(af, bf, acc[n], 0, 0, 0);
        }
      }
#pragma unroll
      for (int n = 0; n < 4; ++n)
#pragma unroll
        for (int r = 0; r < 4; ++r) {
          int t = 16 * m + crow + r, j = 16 * n + rfrag;
          SLbuf[(long)blk * 4096 + t * 64 + j] = (j < t) ? f2bf(acc[n][r]) : (unsigned short)0;
        }
    }
  }
  __syncthreads();

  if (wid < 2) {
    const int d = lane;
    float x[64];
#pragma unroll
    for (int t = 0; t < 64; ++t) {
      float rhs;
      if (wid == 0) rhs = beta * bf2f(sV[t * 64 + d]);
      else          rhs = alpha * bf2f(*(const unsigned short*)((const char*)sK + swz128(t, 2 * d)));
      float s = 0.f;
#pragma unroll
      for (int j = 0; j < t; ++j) s = fmaf(sA[t * 64 + j], x[j], s);
      x[t] = rhs - alpha * s;
    }
    unsigned short* ob = (wid == 0 ? Ubuf : Wbuf) + (long)blk * 4096 + d;
#pragma unroll
    for (int t = 0; t < 64; ++t) ob[t * 64] = f2bf(x[t]);
  }
}

// ---------------- phase 2: sequential chunk recurrence (R6 version, reverted) ----------------
__global__ __launch_bounds__(256) void chunk_scan(
    const unsigned short* __restrict__ qkv,
    const unsigned short* __restrict__ Ubuf, const unsigned short* __restrict__ Wbuf,
    const unsigned short* __restrict__ SLbuf,
    const float* __restrict__ state_in, unsigned short* __restrict__ ybuf,
    float* __restrict__ state_out) {
  __shared__ __align__(16) unsigned short sQ[64 * 64];   // [t][e] swz
  __shared__ __align__(16) unsigned short sW[64 * 64];   // [t][e] swz
  __shared__ __align__(16) unsigned short sSL[64 * 64];  // [t][j] swz
  __shared__ __align__(16) unsigned short sKT[64 * 64];  // [e][t] swz (K transposed)
  __shared__ __align__(16) unsigned short sU[64 * 16];   // [t][dl] linear (this d-quarter)
  __shared__ __align__(16) unsigned short sGT[16 * 64];  // [dl][t] swz
  __shared__ __align__(16) unsigned short sS[16 * 64];   // [dl][e] swz (bf16 state quarter)

  const int blk = blockIdx.x;          // bh*4 + dq
  const int bh = blk >> 2, dq = blk & 3;
  const int b = bh >> 4, h = bh & 15;
  const int tid = threadIdx.x, wid = tid >> 6, lane = tid & 63;
  const int rfrag = lane & 15, koff = (lane >> 4) * 8, crow = (lane >> 4) * 4;
  const int row = tid >> 2, cg = tid & 3;

  const unsigned short* gpb = qkv + (long)(b * 2048 + row) * 3072 + h * 64 + cg * 16;
  const long tbb = ((long)(bh * 32) * 64 + row) * 64 + cg * 16;
  const long ubb = ((long)(bh * 32) * 64 + (tid >> 1)) * 64 + dq * 16 + (tid & 1) * 8;

  bf16x8 qv0, qv1, kv0, kv1, wv0, wv1, sl0, sl1, uv;
  {
    qv0 = *(const bf16x8*)gpb;
    qv1 = *(const bf16x8*)(gpb + 8);
    kv0 = *(const bf16x8*)(gpb + 1024);
    kv1 = *(const bf16x8*)(gpb + 1024 + 8);
    wv0 = *(const bf16x8*)(Wbuf + tbb);
    wv1 = *(const bf16x8*)(Wbuf + tbb + 8);
    sl0 = *(const bf16x8*)(SLbuf + tbb);
    sl1 = *(const bf16x8*)(SLbuf + tbb + 8);
    uv = (tid < 128) ? *(const bf16x8*)(Ubuf + ubb) : bf16x8{};
  }

  f32x4 sacc;
#pragma unroll
  for (int r = 0; r < 4; ++r)
    sacc[r] = state_in[(long)bh * 4096 + (dq * 16 + crow + r) * 64 + 16 * wid + rfrag];
#pragma unroll
  for (int r = 0; r < 4; ++r)
    *(unsigned short*)((char*)sS + swz128(crow + r, 2 * (16 * wid + rfrag))) = f2bf(sacc[r]);

  for (int c = 0; c < NC_; ++c) {
    *(bf16x8*)((char*)sQ + swz128(row, cg * 32)) = qv0;
    *(bf16x8*)((char*)sQ + swz128(row, cg * 32 + 16)) = qv1;
    *(bf16x8*)((char*)sW + swz128(row, cg * 32)) = wv0;
    *(bf16x8*)((char*)sW + swz128(row, cg * 32 + 16)) = wv1;
    *(bf16x8*)((char*)sSL + swz128(row, cg * 32)) = sl0;
    *(bf16x8*)((char*)sSL + swz128(row, cg * 32 + 16)) = sl1;
#pragma unroll
    for (int i = 0; i < 8; ++i) {
      *(unsigned short*)((char*)sKT + swz128(cg * 16 + i, 2 * row)) = (unsigned short)kv0[i];
      *(unsigned short*)((char*)sKT + swz128(cg * 16 + 8 + i, 2 * row)) = (unsigned short)kv1[i];
    }
    if (tid < 128) *(bf16x8*)((char*)sU + ((tid >> 1) * 16 + (tid & 1) * 8) * 2) = uv;

    {
      const int cn = (c + 1 < NC_) ? c + 1 : c;
      const unsigned short* gp = gpb + (long)cn * 64 * 3072;
      const long tb = tbb + (long)cn * 4096;
      qv0 = *(const bf16x8*)gp;
      qv1 = *(const bf16x8*)(gp + 8);
      kv0 = *(const bf16x8*)(gp + 1024);
      kv1 = *(const bf16x8*)(gp + 1024 + 8);
      wv0 = *(const bf16x8*)(Wbuf + tb);
      wv1 = *(const bf16x8*)(Wbuf + tb + 8);
      sl0 = *(const bf16x8*)(SLbuf + tb);
      sl1 = *(const bf16x8*)(SLbuf + tb + 8);
      if (tid < 128) uv = *(const bf16x8*)(Ubuf + ubb + (long)cn * 4096);
    }
    LDS_BARRIER();   // #1

    const int ta = 16 * wid + rfrag;
    f32x4 p = {};
    f32x4 yac = {};
#pragma unroll
    for (int ks = 0; ks < 2; ++ks) {
      bf16x8 afw = *(const bf16x8*)((const char*)sW + swz128(ta, ks * 64 + koff * 2));
      bf16x8 afq = *(const bf16x8*)((const char*)sQ + swz128(ta, ks * 64 + koff * 2));
      bf16x8 bS = *(const bf16x8*)((const char*)sS + swz128(rfrag, ks * 64 + koff * 2));
      p = __builtin_amdgcn_mfma_f32_16x16x32_bf16(afw, bS, p, 0, 0, 0);
      yac = __builtin_amdgcn_mfma_f32_16x16x32_bf16(afq, bS, yac, 0, 0, 0);
    }
#pragma unroll
    for (int r = 0; r < 4; ++r) {
      int t = 16 * wid + crow + r;
      float gg = bf2f(sU[t * 16 + rfrag]) - p[r];
      *(unsigned short*)((char*)sGT + swz128(rfrag, 2 * t)) = f2bf(gg);
    }
    LDS_BARRIER();   // #2

#pragma unroll
    for (int ks = 0; ks < 2; ++ks) {
      bf16x8 aSL = *(const bf16x8*)((const char*)sSL + swz128(ta, ks * 64 + koff * 2));
      bf16x8 bGT = *(const bf16x8*)((const char*)sGT + swz128(rfrag, ks * 64 + koff * 2));
      yac = __builtin_amdgcn_mfma_f32_16x16x32_bf16(aSL, bGT, yac, 0, 0, 0);
    }
#pragma unroll
    for (int r = 0; r < 4; ++r) {
      int t = 16 * wid + crow + r;
      ybuf[(long)(b * 2048 + c * 64 + t) * 1024 + h * 64 + dq * 16 + rfrag] = f2bf(yac[r]);
    }
#pragma unroll
    for (int ks = 0; ks < 2; ++ks) {
      bf16x8 aGT = *(const bf16x8*)((const char*)sGT + swz128(rfrag, ks * 64 + koff * 2));
      bf16x8 bKT = *(const bf16x8*)((const char*)sKT + swz128(16 * wid + rfrag, ks * 64 + koff * 2));
      sacc = __builtin_amdgcn_mfma_f32_16x16x32_bf16(aGT, bKT, sacc, 0, 0, 0);
    }
    LDS_BARRIER();   // #3

#pragma unroll
    for (int r = 0; r < 4; ++r)
      *(unsigned short*)((char*)sS + swz128(crow + r, 2 * (16 * wid + rfrag))) = f2bf(sacc[r]);
  }

#pragma unroll
  for (int r = 0; r < 4; ++r)
    state_out[(long)bh * 4096 + (dq * 16 + crow + r) * 64 + 16 * wid + rfrag] = sacc[r];
}

// ---------------- launch ----------------
extern "C" void kernel_launch(void* const* d_in, const int* in_sizes, int n_in,
                              void* d_out, int out_size, void* d_ws, size_t ws_size,
                              hipStream_t stream) {
  (void)in_sizes; (void)n_in; (void)out_size; (void)ws_size;
  const float* x     = (const float*)d_in[0];
  const float* Wq    = (const float*)d_in[1];
  const float* Wk    = (const float*)d_in[2];
  const float* Wv    = (const float*)d_in[3];
  const float* Wproj = (const float*)d_in[4];
  const float* a_raw = (const float*)d_in[5];
  const float* b_raw = (const float*)d_in[6];
  const float* state = (const float*)d_in[7];

  char* ws = (char*)d_ws;
  unsigned short* xbf = (unsigned short*)ws;                    // 16MB; reused as y
  unsigned short* W3  = (unsigned short*)(ws + (16l << 20));    // 6MB [Wq;Wk;Wv]
  unsigned short* Wp  = (unsigned short*)(ws + (22l << 20));    // 2MB
  unsigned short* qkv = (unsigned short*)(ws + (24l << 20));    // 48MB
  unsigned short* Ub  = (unsigned short*)(ws + (72l << 20));    // 16MB
  unsigned short* Wb  = (unsigned short*)(ws + (88l << 20));    // 16MB
  unsigned short* SLb = (unsigned short*)(ws + (104l << 20));   // 16MB -> 120MB total
  float* out = (float*)d_out;
  float* state_out = out + (long)B_ * T_ * C_;

  cvt_kernel<<<dim3(8192), dim3(256), 0, stream>>>(x, xbf, 8388608);
  cvt_w_kernel<<<dim3(4096), dim3(256), 0, stream>>>(Wq, Wk, Wv, Wproj, W3, Wp);

  gemm256_bt<<<dim3(3072 / 256, 8192 / 256), dim3(512), 0, stream>>>(xbf, W3, qkv, 3072);

  chunk_prep<<<dim3(2048), dim3(256), 0, stream>>>(qkv, a_raw, b_raw, Ub, Wb, SLb);
  chunk_scan<<<dim3(256), dim3(256), 0, stream>>>(qkv, Ub, Wb, SLb, state, xbf, state_out);

  gemm_bt<0><<<dim3(1024 / 128, 8192 / 128), dim3(256), 0, stream>>>(xbf, Wp, (void*)out, 8192, 1024, 1024);
}

// Round 10
// 186.978 us; speedup vs baseline: 1.1943x; 1.1064x over previous
//
#include <hip/hip_runtime.h>
#include <hip/hip_bf16.h>
#include <cstdint>

#define B_ 4
#define T_ 2048
#define C_ 1024
#define H_ 16
#define D_ 64
#define NC_ 32   // chunks
#define L_ 64    // chunk length

typedef __attribute__((ext_vector_type(8))) short bf16x8;
typedef __attribute__((ext_vector_type(4))) float f32x4;

static __device__ __forceinline__ unsigned short f2bf(float f) {
  unsigned u = __float_as_uint(f);
  u += 0x7fff + ((u >> 16) & 1);   // round-to-nearest-even
  return (unsigned short)(u >> 16);
}
static __device__ __forceinline__ float bf2f(unsigned short b) {
  return __uint_as_float(((unsigned)b) << 16);
}
// XOR swizzle for 128B-stride LDS rows (T2): keeps 16B alignment, <=2-way conflicts
static __device__ __forceinline__ int swz128(int row, int byte) {
  return row * 128 + (byte ^ ((row & 7) << 4));
}

// Barrier that does NOT drain vmcnt (T4): LDS edges fenced via lgkmcnt(0).
#define LDS_BARRIER() asm volatile("s_waitcnt lgkmcnt(0)\ns_barrier" ::: "memory")

// ---------------- f32 -> bf16 convert ----------------
__global__ __launch_bounds__(256) void cvt_kernel(const float* __restrict__ src,
                                                  unsigned short* __restrict__ dst, int n) {
  int i = (blockIdx.x * 256 + threadIdx.x) * 4;
  if (i >= n) return;
  float4 v = *reinterpret_cast<const float4*>(src + i);
  ushort4 o;
  o.x = f2bf(v.x); o.y = f2bf(v.y); o.z = f2bf(v.z); o.w = f2bf(v.w);
  *reinterpret_cast<ushort4*>(dst + i) = o;
}

// 4 weight matrices in one launch
__global__ __launch_bounds__(256) void cvt_w_kernel(const float* __restrict__ wq,
                                                    const float* __restrict__ wk,
                                                    const float* __restrict__ wv,
                                                    const float* __restrict__ wp,
                                                    unsigned short* __restrict__ W3,
                                                    unsigned short* __restrict__ Wp) {
  const int g = blockIdx.x >> 10;
  const float* src = (g == 0) ? wq : (g == 1) ? wk : (g == 2) ? wv : wp;
  unsigned short* dst = (g < 3) ? (W3 + (long)g * 1048576) : Wp;
  int i = ((blockIdx.x & 1023) * 256 + threadIdx.x) * 4;
  float4 v = *reinterpret_cast<const float4*>(src + i);
  ushort4 o;
  o.x = f2bf(v.x); o.y = f2bf(v.y); o.z = f2bf(v.z); o.w = f2bf(v.w);
  *reinterpret_cast<ushort4*>(dst + i) = o;
}

// ================= 8-phase 256x256 bf16 GEMM (T1+T2+T3+T4+T5) ==========
#define STAGE256(GP, GR0, KT, LOFF) do {                                          \
    const unsigned short* _s = (GP) + ((GR0) + wid * 8 + lr8) * 1024L             \
                               + (long)(KT) * 64 + skb * 8;                       \
    char* _d = (char*)lds + (LOFF) + wid * 1024;                                  \
    __builtin_amdgcn_global_load_lds((const __attribute__((address_space(1))) void*)_s,      \
        (__attribute__((address_space(3))) void*)_d, 16, 0, 0);                   \
    __builtin_amdgcn_global_load_lds((const __attribute__((address_space(1))) void*)(_s + 64 * 1024L), \
        (__attribute__((address_space(3))) void*)(_d + 8192), 16, 0, 0);          \
  } while (0)

#define PHASE256(AO, BO, MH, NH, STG) do {                                        \
    asm volatile("s_waitcnt vmcnt(6)" ::: "memory");                              \
    bf16x8 av[4][2], bv[2][2];                                                    \
    {                                                                             \
      const char* ab = (const char*)lds + (AO) + (MH) * 16384 + arow;             \
      const char* bb = (const char*)lds + (BO) + (NH) * 16384 + brow;             \
      _Pragma("unroll")                                                           \
      for (int j = 0; j < 4; ++j) {                                               \
        av[j][0] = *(const bf16x8*)(ab + j * 4096 + cb0);                         \
        av[j][1] = *(const bf16x8*)(ab + j * 4096 + cb1);                         \
      }                                                                           \
      _Pragma("unroll")                                                           \
      for (int j2 = 0; j2 < 2; ++j2) {                                            \
        bv[j2][0] = *(const bf16x8*)(bb + j2 * 8192 + cb0);                       \
        bv[j2][1] = *(const bf16x8*)(bb + j2 * 8192 + cb1);                       \
      }                                                                           \
    }                                                                             \
    STG;                                                                          \
    __builtin_amdgcn_s_barrier();                                                 \
    asm volatile("s_waitcnt lgkmcnt(0)" ::: "memory");                            \
    __builtin_amdgcn_sched_barrier(0);                                            \
    __builtin_amdgcn_s_setprio(1);                                                \
    _Pragma("unroll")                                                             \
    for (int j = 0; j < 4; ++j)                                                   \
      _Pragma("unroll")                                                           \
      for (int j2 = 0; j2 < 2; ++j2)                                              \
        acc[(MH) * 4 + j][(NH) * 2 + j2] = __builtin_amdgcn_mfma_f32_16x16x32_bf16( \
            av[j][0], bv[j2][0], acc[(MH) * 4 + j][(NH) * 2 + j2], 0, 0, 0);      \
    _Pragma("unroll")                                                             \
    for (int j = 0; j < 4; ++j)                                                   \
      _Pragma("unroll")                                                           \
      for (int j2 = 0; j2 < 2; ++j2)                                              \
        acc[(MH) * 4 + j][(NH) * 2 + j2] = __builtin_amdgcn_mfma_f32_16x16x32_bf16( \
            av[j][1], bv[j2][1], acc[(MH) * 4 + j][(NH) * 2 + j2], 0, 0, 0);      \
    __builtin_amdgcn_s_setprio(0);                                                \
    __builtin_amdgcn_s_barrier();                                                 \
  } while (0)

__global__ __launch_bounds__(512, 2) void gemm256_bt(
    const unsigned short* __restrict__ A,
    const unsigned short* __restrict__ Bw,
    unsigned short* __restrict__ C, int N) {
  __shared__ __align__(16) char lds[131072];
  enum { EA = 0, EB = 32768, OA = 65536, OB = 98304, HF = 16384 };
  const int tid = threadIdx.x;
  const int wid = tid >> 6, lane = tid & 63;
  const int wm = wid >> 2, wn = wid & 3;
  const int f = lane & 15, g = lane >> 4;
  const int lr8 = lane >> 3, lc = lane & 7;
  const int skb = lc ^ lr8;
  // T1: bijective XCD-chunked swizzle (nwg % 8 == 0)
  const int bid = blockIdx.y * gridDim.x + blockIdx.x;
  const int cpx = (gridDim.x * gridDim.y) >> 3;
  const int sw = (bid & 7) * cpx + (bid >> 3);
  const long bM = (long)(sw / gridDim.x) * 256;
  const long bN = (long)(sw % gridDim.x) * 256;
  const int cb0 = ((0 + g) ^ (f & 7)) * 16;
  const int cb1 = ((4 + g) ^ (f & 7)) * 16;
  const int arow = (wm * 16 + f) * 128;
  const int brow = (wn * 16 + f) * 128;

  f32x4 acc[8][4] = {};

  STAGE256(A, bM, 0, EA);
  STAGE256(Bw, bN, 0, EB);
  STAGE256(A, bM + 128, 0, EA + HF);
  STAGE256(Bw, bN + 128, 0, EB + HF);
  STAGE256(Bw, bN, 1, OB);
  STAGE256(A, bM, 1, OA);
  asm volatile("s_waitcnt vmcnt(8)" ::: "memory");
  __builtin_amdgcn_s_barrier();

  for (int i = 0; i < 8; ++i) {
    const int todd = 2 * i + 1;
    int te = 2 * i + 2; if (te > 14) te = 14;
    int to = 2 * i + 3; if (to > 15) to = 15;
    PHASE256(EA, EB, 0, 0, STAGE256(A, bM + 128, todd, OA + HF));
    PHASE256(EA, EB, 1, 0, STAGE256(Bw, bN + 128, todd, OB + HF));
    PHASE256(EA, EB, 0, 1, STAGE256(Bw, bN, te, EB));
    PHASE256(EA, EB, 1, 1, STAGE256(A, bM, te, EA));
    PHASE256(OA, OB, 0, 0, STAGE256(A, bM + 128, te, EA + HF));
    PHASE256(OA, OB, 1, 0, STAGE256(Bw, bN + 128, te, EB + HF));
    PHASE256(OA, OB, 0, 1, STAGE256(Bw, bN, to, OB));
    PHASE256(OA, OB, 1, 1, STAGE256(A, bM, to, OA));
  }

#pragma unroll
  for (int mf = 0; mf < 8; ++mf) {
    long row = bM + (mf >> 2) * 128 + (mf & 3) * 32 + wm * 16 + g * 4;
#pragma unroll
    for (int nf = 0; nf < 4; ++nf) {
      long col = bN + (nf >> 1) * 128 + (nf & 1) * 64 + wn * 16 + f;
#pragma unroll
      for (int r = 0; r < 4; ++r)
        C[(row + r) * (long)N + col] = f2bf(acc[mf][nf][r]);
    }
  }
}

// ---------------- m97-style 128x128 GEMM (gemm2) ----------------
template<int OUT_BF16>
__global__ __launch_bounds__(256) void gemm_bt(const unsigned short* __restrict__ A,
                                               const unsigned short* __restrict__ Bw,
                                               void* __restrict__ Cp,
                                               int M, int N, int K) {
  __shared__ __align__(16) unsigned short sA[128 * 32];
  __shared__ __align__(16) unsigned short sB[128 * 32];
  const int tid = threadIdx.x;
  const int wid = tid >> 6, lane = tid & 63;
  const int wm = wid >> 1, wn = wid & 1;
  const int bid = blockIdx.y * gridDim.x + blockIdx.x;
  const int cpx = (gridDim.x * gridDim.y) >> 3;
  const int sw = (bid & 7) * cpx + (bid >> 3);
  const long blockM = (long)(sw / gridDim.x) * 128;
  const long blockN = (long)(sw % gridDim.x) * 128;

  f32x4 acc[4][4] = {};

  const int ar = lane >> 2;
  const int ac = (lane & 3) * 8;
  const unsigned short* Abase = A + (blockM + wid * 32 + ar) * (long)K + ac;
  const unsigned short* Bbase = Bw + (blockN + wid * 32 + ar) * (long)K + ac;
  char* sAb = (char*)sA + wid * 2048;
  char* sBb = (char*)sB + wid * 2048;

  for (int k0 = 0; k0 < K; k0 += 32) {
    __syncthreads();
    __builtin_amdgcn_global_load_lds((const __attribute__((address_space(1))) void*)(Abase + k0),
                                     (__attribute__((address_space(3))) void*)(sAb), 16, 0, 0);
    __builtin_amdgcn_global_load_lds((const __attribute__((address_space(1))) void*)(Abase + 16 * (long)K + k0),
                                     (__attribute__((address_space(3))) void*)(sAb + 1024), 16, 0, 0);
    __builtin_amdgcn_global_load_lds((const __attribute__((address_space(1))) void*)(Bbase + k0),
                                     (__attribute__((address_space(3))) void*)(sBb), 16, 0, 0);
    __builtin_amdgcn_global_load_lds((const __attribute__((address_space(1))) void*)(Bbase + 16 * (long)K + k0),
                                     (__attribute__((address_space(3))) void*)(sBb + 1024), 16, 0, 0);
    __syncthreads();

    const int koff = (lane >> 4) * 8;
    const int rA = wm * 64 + (lane & 15);
    const int rB = wn * 64 + (lane & 15);
    bf16x8 af[4], bfr[4];
#pragma unroll
    for (int m = 0; m < 4; ++m)
      af[m] = *reinterpret_cast<const bf16x8*>(&sA[(rA + m * 16) * 32 + koff]);
#pragma unroll
    for (int n = 0; n < 4; ++n)
      bfr[n] = *reinterpret_cast<const bf16x8*>(&sB[(rB + n * 16) * 32 + koff]);
#pragma unroll
    for (int m = 0; m < 4; ++m)
#pragma unroll
      for (int n = 0; n < 4; ++n)
        acc[m][n] = __builtin_amdgcn_mfma_f32_16x16x32_bf16(af[m], bfr[n], acc[m][n], 0, 0, 0);
  }

  const int cr = (lane >> 4) * 4;
  const int cc = lane & 15;
#pragma unroll
  for (int m = 0; m < 4; ++m) {
    long R = blockM + wm * 64 + m * 16 + cr;
#pragma unroll
    for (int n = 0; n < 4; ++n) {
      long Cc = blockN + wn * 64 + n * 16 + cc;
#pragma unroll
      for (int r = 0; r < 4; ++r) {
        if (OUT_BF16)
          ((unsigned short*)Cp)[(R + r) * (long)N + Cc] = f2bf(acc[m][n][r]);
        else
          ((float*)Cp)[(R + r) * (long)N + Cc] = acc[m][n][r];
      }
    }
  }
}

// ---------------- phase 1: per (bh, chunk) WY precompute ----------------
// Also packs KT = K^T (normalized) into the dead V-slot of qkv (V is consumed
// into U here; scan reads KT from the V-slot). Transpose cost moved from the
// serial scan loop into this fully-parallel kernel.
__global__ __launch_bounds__(256) void chunk_prep(
    unsigned short* __restrict__ qkv,
    const float* __restrict__ a_raw, const float* __restrict__ b_raw,
    unsigned short* __restrict__ Ubuf, unsigned short* __restrict__ Wbuf,
    unsigned short* __restrict__ SLbuf) {
  __shared__ __align__(16) unsigned short sK[64 * 64];
  __shared__ __align__(16) unsigned short sQ[64 * 64];
  __shared__ __align__(16) unsigned short sV[64 * 64];
  __shared__ float sA[64 * 64];

  const int blk = blockIdx.x;           // bh*32 + c
  const int bh = blk >> 5, c = blk & 31;
  const int b = bh >> 4, h = bh & 15;
  const int tid = threadIdx.x;
  const int wid = tid >> 6, lane = tid & 63;

  const float alpha = 0.5f / (1.f + __expf(-a_raw[h]));
  const float beta  = 0.5f / (1.f + __expf(-b_raw[h]));

  {
    const int row = tid >> 2, cg = tid & 3;
    unsigned short* gp = qkv + (long)(b * 2048 + c * 64 + row) * 3072 + h * 64 + cg * 16;
    bf16x8 q0 = *(const bf16x8*)(gp);
    bf16x8 q1 = *(const bf16x8*)(gp + 8);
    bf16x8 k0 = *(const bf16x8*)(gp + 1024);
    bf16x8 k1 = *(const bf16x8*)(gp + 1024 + 8);
    bf16x8 v0 = *(const bf16x8*)(gp + 2048);
    bf16x8 v1 = *(const bf16x8*)(gp + 2048 + 8);
    float kf[16];
    float ss = 0.f;
#pragma unroll
    for (int i = 0; i < 8; ++i) { kf[i] = bf2f((unsigned short)k0[i]); ss += kf[i] * kf[i]; }
#pragma unroll
    for (int i = 0; i < 8; ++i) { kf[8 + i] = bf2f((unsigned short)k1[i]); ss += kf[8 + i] * kf[8 + i]; }
    ss += __shfl_xor(ss, 1);
    ss += __shfl_xor(ss, 2);
    const float inv = 1.f / fmaxf(sqrtf(ss), 1e-12f);
    bf16x8 n0, n1;
#pragma unroll
    for (int i = 0; i < 8; ++i) { n0[i] = (short)f2bf(kf[i] * inv); n1[i] = (short)f2bf(kf[8 + i] * inv); }
    *(bf16x8*)((char*)sK + swz128(row, cg * 32)) = n0;
    *(bf16x8*)((char*)sK + swz128(row, cg * 32 + 16)) = n1;
    *(bf16x8*)((char*)sQ + swz128(row, cg * 32)) = q0;
    *(bf16x8*)((char*)sQ + swz128(row, cg * 32 + 16)) = q1;
    *(bf16x8*)((char*)sV + row * 128 + cg * 32) = v0;
    *(bf16x8*)((char*)sV + row * 128 + cg * 32 + 16) = v1;
  }
  __syncthreads();

  // KT pack: slot[e][t] = K_norm[t][e] -> qkv V-slot (coalesced bf16x8 stores)
  {
    const int erow = tid >> 2, tq = tid & 3;
    unsigned short kt[16];
#pragma unroll
    for (int i = 0; i < 16; ++i)
      kt[i] = *(const unsigned short*)((const char*)sK + swz128(tq * 16 + i, 2 * erow));
    unsigned short* vp = qkv + (long)(b * 2048 + c * 64 + erow) * 3072 + 2048 + h * 64 + tq * 16;
    *(bf16x8*)vp = *(const bf16x8*)kt;
    *(bf16x8*)(vp + 8) = *(const bf16x8*)(kt + 8);
  }

  const int rfrag = lane & 15, koff = (lane >> 4) * 8, crow = (lane >> 4) * 4;
  const int w2 = wid & 1;
  if (wid < 2) {
#pragma unroll
    for (int mt = 0; mt < 2; ++mt) {
      const int m = w2 * 2 + mt;
      const int ra = 16 * m + rfrag;
      f32x4 acc[4] = {};
#pragma unroll
      for (int ks = 0; ks < 2; ++ks) {
        bf16x8 af = *(const bf16x8*)((const char*)sK + swz128(ra, ks * 64 + koff * 2));
#pragma unroll
        for (int n = 0; n < 4; ++n) {
          bf16x8 bf = *(const bf16x8*)((const char*)sK + swz128(16 * n + rfrag, ks * 64 + koff * 2));
          acc[n] = __builtin_amdgcn_mfma_f32_16x16x32_bf16(af, bf, acc[n], 0, 0, 0);
        }
      }
#pragma unroll
      for (int n = 0; n < 4; ++n)
#pragma unroll
        for (int r = 0; r < 4; ++r)
          sA[(16 * m + crow + r) * 64 + 16 * n + rfrag] = acc[n][r];
    }
  } else {
#pragma unroll
    for (int mt = 0; mt < 2; ++mt) {
      const int m = w2 * 2 + mt;
      const int ra = 16 * m + rfrag;
      f32x4 acc[4] = {};
#pragma unroll
      for (int ks = 0; ks < 2; ++ks) {
        bf16x8 af = *(const bf16x8*)((const char*)sQ + swz128(ra, ks * 64 + koff * 2));
#pragma unroll
        for (int n = 0; n < 4; ++n) {
          bf16x8 bf = *(const bf16x8*)((const char*)sK + swz128(16 * n + rfrag, ks * 64 + koff * 2));
          acc[n] = __builtin_amdgcn_mfma_f32_16x16x32_bf16(af, bf, acc[n], 0, 0, 0);
        }
      }
#pragma unroll
      for (int n = 0; n < 4; ++n)
#pragma unroll
        for (int r = 0; r < 4; ++r) {
          int t = 16 * m + crow + r, j = 16 * n + rfrag;
          SLbuf[(long)blk * 4096 + t * 64 + j] = (j < t) ? f2bf(acc[n][r]) : (unsigned short)0;
        }
    }
  }
  __syncthreads();

  if (wid < 2) {
    const int d = lane;
    float x[64];
#pragma unroll
    for (int t = 0; t < 64; ++t) {
      float rhs;
      if (wid == 0) rhs = beta * bf2f(sV[t * 64 + d]);
      else          rhs = alpha * bf2f(*(const unsigned short*)((const char*)sK + swz128(t, 2 * d)));
      float s = 0.f;
#pragma unroll
      for (int j = 0; j < t; ++j) s = fmaf(sA[t * 64 + j], x[j], s);
      x[t] = rhs - alpha * s;
    }
    unsigned short* ob = (wid == 0 ? Ubuf : Wbuf) + (long)blk * 4096 + d;
#pragma unroll
    for (int t = 0; t < 64; ++t) ob[t * 64] = f2bf(x[t]);
  }
}

// ---------------- phase 2: sequential chunk recurrence ----------------
// KT now loaded pre-transposed from the qkv V-slot: staging is 9 vectorized
// b128 writes/thread (was 7 b128 + 16 scalar b16). XCD-chunked block swizzle
// co-locates the 4 dq-blocks of each bh on one XCD (shared-tile L2 reuse).
__global__ __launch_bounds__(256) void chunk_scan(
    const unsigned short* __restrict__ qkv,
    const unsigned short* __restrict__ Ubuf, const unsigned short* __restrict__ Wbuf,
    const unsigned short* __restrict__ SLbuf,
    const float* __restrict__ state_in, unsigned short* __restrict__ ybuf,
    float* __restrict__ state_out) {
  __shared__ __align__(16) unsigned short sQ[64 * 64];   // [t][e] swz
  __shared__ __align__(16) unsigned short sW[64 * 64];   // [t][e] swz
  __shared__ __align__(16) unsigned short sSL[64 * 64];  // [t][j] swz
  __shared__ __align__(16) unsigned short sKT[64 * 64];  // [e][t] swz
  __shared__ __align__(16) unsigned short sU[64 * 16];   // [t][dl] linear
  __shared__ __align__(16) unsigned short sGT[16 * 64];  // [dl][t] swz
  __shared__ __align__(16) unsigned short sS[16 * 64];   // [dl][e] swz

  const int bid0 = blockIdx.x;
  const int blk = (bid0 & 7) * 32 + (bid0 >> 3);   // T1: XCD-chunked (256%8==0)
  const int bh = blk >> 2, dq = blk & 3;
  const int b = bh >> 4, h = bh & 15;
  const int tid = threadIdx.x, wid = tid >> 6, lane = tid & 63;
  const int rfrag = lane & 15, koff = (lane >> 4) * 8, crow = (lane >> 4) * 4;
  const int row = tid >> 2, cg = tid & 3;

  const unsigned short* gpb = qkv + (long)(b * 2048 + row) * 3072 + h * 64 + cg * 16;
  const long tbb = ((long)(bh * 32) * 64 + row) * 64 + cg * 16;
  const long ubb = ((long)(bh * 32) * 64 + (tid >> 1)) * 64 + dq * 16 + (tid & 1) * 8;

  bf16x8 qv0, qv1, kt0, kt1, wv0, wv1, sl0, sl1, uv;
  {
    qv0 = *(const bf16x8*)gpb;
    qv1 = *(const bf16x8*)(gpb + 8);
    kt0 = *(const bf16x8*)(gpb + 2048);      // KT slot (row = e)
    kt1 = *(const bf16x8*)(gpb + 2048 + 8);
    wv0 = *(const bf16x8*)(Wbuf + tbb);
    wv1 = *(const bf16x8*)(Wbuf + tbb + 8);
    sl0 = *(const bf16x8*)(SLbuf + tbb);
    sl1 = *(const bf16x8*)(SLbuf + tbb + 8);
    uv = (tid < 128) ? *(const bf16x8*)(Ubuf + ubb) : bf16x8{};
  }

  f32x4 sacc;
#pragma unroll
  for (int r = 0; r < 4; ++r)
    sacc[r] = state_in[(long)bh * 4096 + (dq * 16 + crow + r) * 64 + 16 * wid + rfrag];
#pragma unroll
  for (int r = 0; r < 4; ++r)
    *(unsigned short*)((char*)sS + swz128(crow + r, 2 * (16 * wid + rfrag))) = f2bf(sacc[r]);

  for (int c = 0; c < NC_; ++c) {
    *(bf16x8*)((char*)sQ + swz128(row, cg * 32)) = qv0;
    *(bf16x8*)((char*)sQ + swz128(row, cg * 32 + 16)) = qv1;
    *(bf16x8*)((char*)sW + swz128(row, cg * 32)) = wv0;
    *(bf16x8*)((char*)sW + swz128(row, cg * 32 + 16)) = wv1;
    *(bf16x8*)((char*)sSL + swz128(row, cg * 32)) = sl0;
    *(bf16x8*)((char*)sSL + swz128(row, cg * 32 + 16)) = sl1;
    *(bf16x8*)((char*)sKT + swz128(row, cg * 32)) = kt0;       // row = e
    *(bf16x8*)((char*)sKT + swz128(row, cg * 32 + 16)) = kt1;
    if (tid < 128) *(bf16x8*)((char*)sU + ((tid >> 1) * 16 + (tid & 1) * 8) * 2) = uv;

    {
      const int cn = (c + 1 < NC_) ? c + 1 : c;
      const unsigned short* gp = gpb + (long)cn * 64 * 3072;
      const long tb = tbb + (long)cn * 4096;
      qv0 = *(const bf16x8*)gp;
      qv1 = *(const bf16x8*)(gp + 8);
      kt0 = *(const bf16x8*)(gp + 2048);
      kt1 = *(const bf16x8*)(gp + 2048 + 8);
      wv0 = *(const bf16x8*)(Wbuf + tb);
      wv1 = *(const bf16x8*)(Wbuf + tb + 8);
      sl0 = *(const bf16x8*)(SLbuf + tb);
      sl1 = *(const bf16x8*)(SLbuf + tb + 8);
      if (tid < 128) uv = *(const bf16x8*)(Ubuf + ubb + (long)cn * 4096);
    }
    LDS_BARRIER();   // #1

    const int ta = 16 * wid + rfrag;
    f32x4 p = {};
    f32x4 yac = {};
#pragma unroll
    for (int ks = 0; ks < 2; ++ks) {
      bf16x8 afw = *(const bf16x8*)((const char*)sW + swz128(ta, ks * 64 + koff * 2));
      bf16x8 afq = *(const bf16x8*)((const char*)sQ + swz128(ta, ks * 64 + koff * 2));
      bf16x8 bS = *(const bf16x8*)((const char*)sS + swz128(rfrag, ks * 64 + koff * 2));
      p = __builtin_amdgcn_mfma_f32_16x16x32_bf16(afw, bS, p, 0, 0, 0);
      yac = __builtin_amdgcn_mfma_f32_16x16x32_bf16(afq, bS, yac, 0, 0, 0);
    }
#pragma unroll
    for (int r = 0; r < 4; ++r) {
      int t = 16 * wid + crow + r;
      float gg = bf2f(sU[t * 16 + rfrag]) - p[r];
      *(unsigned short*)((char*)sGT + swz128(rfrag, 2 * t)) = f2bf(gg);
    }
    LDS_BARRIER();   // #2

#pragma unroll
    for (int ks = 0; ks < 2; ++ks) {
      bf16x8 aSL = *(const bf16x8*)((const char*)sSL + swz128(ta, ks * 64 + koff * 2));
      bf16x8 bGT = *(const bf16x8*)((const char*)sGT + swz128(rfrag, ks * 64 + koff * 2));
      yac = __builtin_amdgcn_mfma_f32_16x16x32_bf16(aSL, bGT, yac, 0, 0, 0);
    }
#pragma unroll
    for (int r = 0; r < 4; ++r) {
      int t = 16 * wid + crow + r;
      ybuf[(long)(b * 2048 + c * 64 + t) * 1024 + h * 64 + dq * 16 + rfrag] = f2bf(yac[r]);
    }
#pragma unroll
    for (int ks = 0; ks < 2; ++ks) {
      bf16x8 aGT = *(const bf16x8*)((const char*)sGT + swz128(rfrag, ks * 64 + koff * 2));
      bf16x8 bKT = *(const bf16x8*)((const char*)sKT + swz128(16 * wid + rfrag, ks * 64 + koff * 2));
      sacc = __builtin_amdgcn_mfma_f32_16x16x32_bf16(aGT, bKT, sacc, 0, 0, 0);
    }
    LDS_BARRIER();   // #3

#pragma unroll
    for (int r = 0; r < 4; ++r)
      *(unsigned short*)((char*)sS + swz128(crow + r, 2 * (16 * wid + rfrag))) = f2bf(sacc[r]);
  }

#pragma unroll
  for (int r = 0; r < 4; ++r)
    state_out[(long)bh * 4096 + (dq * 16 + crow + r) * 64 + 16 * wid + rfrag] = sacc[r];
}

// ---------------- launch ----------------
extern "C" void kernel_launch(void* const* d_in, const int* in_sizes, int n_in,
                              void* d_out, int out_size, void* d_ws, size_t ws_size,
                              hipStream_t stream) {
  (void)in_sizes; (void)n_in; (void)out_size; (void)ws_size;
  const float* x     = (const float*)d_in[0];
  const float* Wq    = (const float*)d_in[1];
  const float* Wk    = (const float*)d_in[2];
  const float* Wv    = (const float*)d_in[3];
  const float* Wproj = (const float*)d_in[4];
  const float* a_raw = (const float*)d_in[5];
  const float* b_raw = (const float*)d_in[6];
  const float* state = (const float*)d_in[7];

  char* ws = (char*)d_ws;
  unsigned short* xbf = (unsigned short*)ws;                    // 16MB; reused as y
  unsigned short* W3  = (unsigned short*)(ws + (16l << 20));    // 6MB [Wq;Wk;Wv]
  unsigned short* Wp  = (unsigned short*)(ws + (22l << 20));    // 2MB
  unsigned short* qkv = (unsigned short*)(ws + (24l << 20));    // 48MB
  unsigned short* Ub  = (unsigned short*)(ws + (72l << 20));    // 16MB
  unsigned short* Wb  = (unsigned short*)(ws + (88l << 20));    // 16MB
  unsigned short* SLb = (unsigned short*)(ws + (104l << 20));   // 16MB -> 120MB total
  float* out = (float*)d_out;
  float* state_out = out + (long)B_ * T_ * C_;

  cvt_kernel<<<dim3(8192), dim3(256), 0, stream>>>(x, xbf, 8388608);
  cvt_w_kernel<<<dim3(4096), dim3(256), 0, stream>>>(Wq, Wk, Wv, Wproj, W3, Wp);

  gemm256_bt<<<dim3(3072 / 256, 8192 / 256), dim3(512), 0, stream>>>(xbf, W3, qkv, 3072);

  chunk_prep<<<dim3(2048), dim3(256), 0, stream>>>(qkv, a_raw, b_raw, Ub, Wb, SLb);
  chunk_scan<<<dim3(256), dim3(256), 0, stream>>>(qkv, Ub, Wb, SLb, state, xbf, state_out);

  gemm_bt<0><<<dim3(1024 / 128, 8192 / 128), dim3(256), 0, stream>>>(xbf, Wp, (void*)out, 8192, 1024, 1024);
}

// Round 11
// 180.818 us; speedup vs baseline: 1.2350x; 1.0341x over previous
//
#include <hip/hip_runtime.h>
#include <hip/hip_bf16.h>
#include <cstdint>

#define B_ 4
#define T_ 2048
#define C_ 1024
#define H_ 16
#define D_ 64
#define NC_ 32   // chunks
#define L_ 64    // chunk length

typedef __attribute__((ext_vector_type(8))) short bf16x8;
typedef __attribute__((ext_vector_type(4))) float f32x4;

static __device__ __forceinline__ unsigned short f2bf(float f) {
  unsigned u = __float_as_uint(f);
  u += 0x7fff + ((u >> 16) & 1);   // round-to-nearest-even
  return (unsigned short)(u >> 16);
}
static __device__ __forceinline__ float bf2f(unsigned short b) {
  return __uint_as_float(((unsigned)b) << 16);
}
// XOR swizzle for 128B-stride LDS rows (T2): keeps 16B alignment, <=2-way conflicts
static __device__ __forceinline__ int swz128(int row, int byte) {
  return row * 128 + (byte ^ ((row & 7) << 4));
}

// Barrier that does NOT drain vmcnt (T4): LDS edges fenced via lgkmcnt(0).
#define LDS_BARRIER() asm volatile("s_waitcnt lgkmcnt(0)\ns_barrier" ::: "memory")

// ---------------- f32 -> bf16 convert (x + 4 weights in ONE launch) ----------------
__global__ __launch_bounds__(256) void cvt_all(const float* __restrict__ x,
                                               const float* __restrict__ wq,
                                               const float* __restrict__ wk,
                                               const float* __restrict__ wv,
                                               const float* __restrict__ wp,
                                               unsigned short* __restrict__ xbf,
                                               unsigned short* __restrict__ W3,
                                               unsigned short* __restrict__ Wp) {
  const int bidx = blockIdx.x;
  const float* src;
  unsigned short* dst;
  long base;
  if (bidx < 8192) {
    src = x; dst = xbf; base = (long)bidx * 1024;
  } else {
    const int g = (bidx - 8192) >> 10;
    src = (g == 0) ? wq : (g == 1) ? wk : (g == 2) ? wv : wp;
    dst = (g < 3) ? (W3 + (long)g * 1048576) : Wp;
    base = (long)((bidx - 8192) & 1023) * 1024;
  }
  long i = base + threadIdx.x * 4;
  float4 v = *reinterpret_cast<const float4*>(src + i);
  ushort4 o;
  o.x = f2bf(v.x); o.y = f2bf(v.y); o.z = f2bf(v.z); o.w = f2bf(v.w);
  *reinterpret_cast<ushort4*>(dst + i) = o;
}

// ================= 8-phase 256x256 bf16 GEMM (T1+T2+T3+T4+T5) ==========
#define STAGE256(GP, GR0, KT, LOFF) do {                                          \
    const unsigned short* _s = (GP) + ((GR0) + wid * 8 + lr8) * 1024L             \
                               + (long)(KT) * 64 + skb * 8;                       \
    char* _d = (char*)lds + (LOFF) + wid * 1024;                                  \
    __builtin_amdgcn_global_load_lds((const __attribute__((address_space(1))) void*)_s,      \
        (__attribute__((address_space(3))) void*)_d, 16, 0, 0);                   \
    __builtin_amdgcn_global_load_lds((const __attribute__((address_space(1))) void*)(_s + 64 * 1024L), \
        (__attribute__((address_space(3))) void*)(_d + 8192), 16, 0, 0);          \
  } while (0)

#define PHASE256(AO, BO, MH, NH, STG) do {                                        \
    asm volatile("s_waitcnt vmcnt(6)" ::: "memory");                              \
    bf16x8 av[4][2], bv[2][2];                                                    \
    {                                                                             \
      const char* ab = (const char*)lds + (AO) + (MH) * 16384 + arow;             \
      const char* bb = (const char*)lds + (BO) + (NH) * 16384 + brow;             \
      _Pragma("unroll")                                                           \
      for (int j = 0; j < 4; ++j) {                                               \
        av[j][0] = *(const bf16x8*)(ab + j * 4096 + cb0);                         \
        av[j][1] = *(const bf16x8*)(ab + j * 4096 + cb1);                         \
      }                                                                           \
      _Pragma("unroll")                                                           \
      for (int j2 = 0; j2 < 2; ++j2) {                                            \
        bv[j2][0] = *(const bf16x8*)(bb + j2 * 8192 + cb0);                       \
        bv[j2][1] = *(const bf16x8*)(bb + j2 * 8192 + cb1);                       \
      }                                                                           \
    }                                                                             \
    STG;                                                                          \
    __builtin_amdgcn_s_barrier();                                                 \
    asm volatile("s_waitcnt lgkmcnt(0)" ::: "memory");                            \
    __builtin_amdgcn_sched_barrier(0);                                            \
    __builtin_amdgcn_s_setprio(1);                                                \
    _Pragma("unroll")                                                             \
    for (int j = 0; j < 4; ++j)                                                   \
      _Pragma("unroll")                                                           \
      for (int j2 = 0; j2 < 2; ++j2)                                              \
        acc[(MH) * 4 + j][(NH) * 2 + j2] = __builtin_amdgcn_mfma_f32_16x16x32_bf16( \
            av[j][0], bv[j2][0], acc[(MH) * 4 + j][(NH) * 2 + j2], 0, 0, 0);      \
    _Pragma("unroll")                                                             \
    for (int j = 0; j < 4; ++j)                                                   \
      _Pragma("unroll")                                                           \
      for (int j2 = 0; j2 < 2; ++j2)                                              \
        acc[(MH) * 4 + j][(NH) * 2 + j2] = __builtin_amdgcn_mfma_f32_16x16x32_bf16( \
            av[j][1], bv[j2][1], acc[(MH) * 4 + j][(NH) * 2 + j2], 0, 0, 0);      \
    __builtin_amdgcn_s_setprio(0);                                                \
    __builtin_amdgcn_s_barrier();                                                 \
  } while (0)

__global__ __launch_bounds__(512, 2) void gemm256_bt(
    const unsigned short* __restrict__ A,
    const unsigned short* __restrict__ Bw,
    unsigned short* __restrict__ C, int N) {
  __shared__ __align__(16) char lds[131072];
  enum { EA = 0, EB = 32768, OA = 65536, OB = 98304, HF = 16384 };
  const int tid = threadIdx.x;
  const int wid = tid >> 6, lane = tid & 63;
  const int wm = wid >> 2, wn = wid & 3;
  const int f = lane & 15, g = lane >> 4;
  const int lr8 = lane >> 3, lc = lane & 7;
  const int skb = lc ^ lr8;
  // T1: bijective XCD-chunked swizzle (nwg % 8 == 0)
  const int bid = blockIdx.y * gridDim.x + blockIdx.x;
  const int cpx = (gridDim.x * gridDim.y) >> 3;
  const int sw = (bid & 7) * cpx + (bid >> 3);
  const long bM = (long)(sw / gridDim.x) * 256;
  const long bN = (long)(sw % gridDim.x) * 256;
  const int cb0 = ((0 + g) ^ (f & 7)) * 16;
  const int cb1 = ((4 + g) ^ (f & 7)) * 16;
  const int arow = (wm * 16 + f) * 128;
  const int brow = (wn * 16 + f) * 128;

  f32x4 acc[8][4] = {};

  STAGE256(A, bM, 0, EA);
  STAGE256(Bw, bN, 0, EB);
  STAGE256(A, bM + 128, 0, EA + HF);
  STAGE256(Bw, bN + 128, 0, EB + HF);
  STAGE256(Bw, bN, 1, OB);
  STAGE256(A, bM, 1, OA);
  asm volatile("s_waitcnt vmcnt(8)" ::: "memory");
  __builtin_amdgcn_s_barrier();

  for (int i = 0; i < 8; ++i) {
    const int todd = 2 * i + 1;
    int te = 2 * i + 2; if (te > 14) te = 14;
    int to = 2 * i + 3; if (to > 15) to = 15;
    PHASE256(EA, EB, 0, 0, STAGE256(A, bM + 128, todd, OA + HF));
    PHASE256(EA, EB, 1, 0, STAGE256(Bw, bN + 128, todd, OB + HF));
    PHASE256(EA, EB, 0, 1, STAGE256(Bw, bN, te, EB));
    PHASE256(EA, EB, 1, 1, STAGE256(A, bM, te, EA));
    PHASE256(OA, OB, 0, 0, STAGE256(A, bM + 128, te, EA + HF));
    PHASE256(OA, OB, 1, 0, STAGE256(Bw, bN + 128, te, EB + HF));
    PHASE256(OA, OB, 0, 1, STAGE256(Bw, bN, to, OB));
    PHASE256(OA, OB, 1, 1, STAGE256(A, bM, to, OA));
  }

#pragma unroll
  for (int mf = 0; mf < 8; ++mf) {
    long row = bM + (mf >> 2) * 128 + (mf & 3) * 32 + wm * 16 + g * 4;
#pragma unroll
    for (int nf = 0; nf < 4; ++nf) {
      long col = bN + (nf >> 1) * 128 + (nf & 1) * 64 + wn * 16 + f;
#pragma unroll
      for (int r = 0; r < 4; ++r)
        C[(row + r) * (long)N + col] = f2bf(acc[mf][nf][r]);
    }
  }
}

// ---------------- m97-style 128x128 GEMM (gemm2) ----------------
template<int OUT_BF16>
__global__ __launch_bounds__(256) void gemm_bt(const unsigned short* __restrict__ A,
                                               const unsigned short* __restrict__ Bw,
                                               void* __restrict__ Cp,
                                               int M, int N, int K) {
  __shared__ __align__(16) unsigned short sA[128 * 32];
  __shared__ __align__(16) unsigned short sB[128 * 32];
  const int tid = threadIdx.x;
  const int wid = tid >> 6, lane = tid & 63;
  const int wm = wid >> 1, wn = wid & 1;
  const int bid = blockIdx.y * gridDim.x + blockIdx.x;
  const int cpx = (gridDim.x * gridDim.y) >> 3;
  const int sw = (bid & 7) * cpx + (bid >> 3);
  const long blockM = (long)(sw / gridDim.x) * 128;
  const long blockN = (long)(sw % gridDim.x) * 128;

  f32x4 acc[4][4] = {};

  const int ar = lane >> 2;
  const int ac = (lane & 3) * 8;
  const unsigned short* Abase = A + (blockM + wid * 32 + ar) * (long)K + ac;
  const unsigned short* Bbase = Bw + (blockN + wid * 32 + ar) * (long)K + ac;
  char* sAb = (char*)sA + wid * 2048;
  char* sBb = (char*)sB + wid * 2048;

  for (int k0 = 0; k0 < K; k0 += 32) {
    __syncthreads();
    __builtin_amdgcn_global_load_lds((const __attribute__((address_space(1))) void*)(Abase + k0),
                                     (__attribute__((address_space(3))) void*)(sAb), 16, 0, 0);
    __builtin_amdgcn_global_load_lds((const __attribute__((address_space(1))) void*)(Abase + 16 * (long)K + k0),
                                     (__attribute__((address_space(3))) void*)(sAb + 1024), 16, 0, 0);
    __builtin_amdgcn_global_load_lds((const __attribute__((address_space(1))) void*)(Bbase + k0),
                                     (__attribute__((address_space(3))) void*)(sBb), 16, 0, 0);
    __builtin_amdgcn_global_load_lds((const __attribute__((address_space(1))) void*)(Bbase + 16 * (long)K + k0),
                                     (__attribute__((address_space(3))) void*)(sBb + 1024), 16, 0, 0);
    __syncthreads();

    const int koff = (lane >> 4) * 8;
    const int rA = wm * 64 + (lane & 15);
    const int rB = wn * 64 + (lane & 15);
    bf16x8 af[4], bfr[4];
#pragma unroll
    for (int m = 0; m < 4; ++m)
      af[m] = *reinterpret_cast<const bf16x8*>(&sA[(rA + m * 16) * 32 + koff]);
#pragma unroll
    for (int n = 0; n < 4; ++n)
      bfr[n] = *reinterpret_cast<const bf16x8*>(&sB[(rB + n * 16) * 32 + koff]);
#pragma unroll
    for (int m = 0; m < 4; ++m)
#pragma unroll
      for (int n = 0; n < 4; ++n)
        acc[m][n] = __builtin_amdgcn_mfma_f32_16x16x32_bf16(af[m], bfr[n], acc[m][n], 0, 0, 0);
  }

  const int cr = (lane >> 4) * 4;
  const int cc = lane & 15;
#pragma unroll
  for (int m = 0; m < 4; ++m) {
    long R = blockM + wm * 64 + m * 16 + cr;
#pragma unroll
    for (int n = 0; n < 4; ++n) {
      long Cc = blockN + wn * 64 + n * 16 + cc;
#pragma unroll
      for (int r = 0; r < 4; ++r) {
        if (OUT_BF16)
          ((unsigned short*)Cp)[(R + r) * (long)N + Cc] = f2bf(acc[m][n][r]);
        else
          ((float*)Cp)[(R + r) * (long)N + Cc] = acc[m][n][r];
      }
    }
  }
}

// ---------------- phase 1: per (bh, chunk) WY precompute ----------------
// Packs KT = K_norm^T into the dead V-slot of qkv (scan stages it vectorized).
__global__ __launch_bounds__(256) void chunk_prep(
    unsigned short* __restrict__ qkv,
    const float* __restrict__ a_raw, const float* __restrict__ b_raw,
    unsigned short* __restrict__ Ubuf, unsigned short* __restrict__ Wbuf,
    unsigned short* __restrict__ SLbuf) {
  __shared__ __align__(16) unsigned short sK[64 * 64];
  __shared__ __align__(16) unsigned short sQ[64 * 64];
  __shared__ __align__(16) unsigned short sV[64 * 64];
  __shared__ float sA[64 * 64];

  const int blk = blockIdx.x;           // bh*32 + c
  const int bh = blk >> 5, c = blk & 31;
  const int b = bh >> 4, h = bh & 15;
  const int tid = threadIdx.x;
  const int wid = tid >> 6, lane = tid & 63;

  const float alpha = 0.5f / (1.f + __expf(-a_raw[h]));
  const float beta  = 0.5f / (1.f + __expf(-b_raw[h]));

  {
    const int row = tid >> 2, cg = tid & 3;
    unsigned short* gp = qkv + (long)(b * 2048 + c * 64 + row) * 3072 + h * 64 + cg * 16;
    bf16x8 q0 = *(const bf16x8*)(gp);
    bf16x8 q1 = *(const bf16x8*)(gp + 8);
    bf16x8 k0 = *(const bf16x8*)(gp + 1024);
    bf16x8 k1 = *(const bf16x8*)(gp + 1024 + 8);
    bf16x8 v0 = *(const bf16x8*)(gp + 2048);
    bf16x8 v1 = *(const bf16x8*)(gp + 2048 + 8);
    float kf[16];
    float ss = 0.f;
#pragma unroll
    for (int i = 0; i < 8; ++i) { kf[i] = bf2f((unsigned short)k0[i]); ss += kf[i] * kf[i]; }
#pragma unroll
    for (int i = 0; i < 8; ++i) { kf[8 + i] = bf2f((unsigned short)k1[i]); ss += kf[8 + i] * kf[8 + i]; }
    ss += __shfl_xor(ss, 1);
    ss += __shfl_xor(ss, 2);
    const float inv = 1.f / fmaxf(sqrtf(ss), 1e-12f);
    bf16x8 n0, n1;
#pragma unroll
    for (int i = 0; i < 8; ++i) { n0[i] = (short)f2bf(kf[i] * inv); n1[i] = (short)f2bf(kf[8 + i] * inv); }
    *(bf16x8*)((char*)sK + swz128(row, cg * 32)) = n0;
    *(bf16x8*)((char*)sK + swz128(row, cg * 32 + 16)) = n1;
    *(bf16x8*)((char*)sQ + swz128(row, cg * 32)) = q0;
    *(bf16x8*)((char*)sQ + swz128(row, cg * 32 + 16)) = q1;
    *(bf16x8*)((char*)sV + row * 128 + cg * 32) = v0;
    *(bf16x8*)((char*)sV + row * 128 + cg * 32 + 16) = v1;
  }
  __syncthreads();

  // KT pack: slot[e][t] = K_norm[t][e] -> qkv V-slot (coalesced bf16x8 stores)
  {
    const int erow = tid >> 2, tq = tid & 3;
    unsigned short kt[16];
#pragma unroll
    for (int i = 0; i < 16; ++i)
      kt[i] = *(const unsigned short*)((const char*)sK + swz128(tq * 16 + i, 2 * erow));
    unsigned short* vp = qkv + (long)(b * 2048 + c * 64 + erow) * 3072 + 2048 + h * 64 + tq * 16;
    *(bf16x8*)vp = *(const bf16x8*)kt;
    *(bf16x8*)(vp + 8) = *(const bf16x8*)(kt + 8);
  }

  const int rfrag = lane & 15, koff = (lane >> 4) * 8, crow = (lane >> 4) * 4;
  const int w2 = wid & 1;
  if (wid < 2) {
#pragma unroll
    for (int mt = 0; mt < 2; ++mt) {
      const int m = w2 * 2 + mt;
      const int ra = 16 * m + rfrag;
      f32x4 acc[4] = {};
#pragma unroll
      for (int ks = 0; ks < 2; ++ks) {
        bf16x8 af = *(const bf16x8*)((const char*)sK + swz128(ra, ks * 64 + koff * 2));
#pragma unroll
        for (int n = 0; n < 4; ++n) {
          bf16x8 bf = *(const bf16x8*)((const char*)sK + swz128(16 * n + rfrag, ks * 64 + koff * 2));
          acc[n] = __builtin_amdgcn_mfma_f32_16x16x32_bf16(af, bf, acc[n], 0, 0, 0);
        }
      }
#pragma unroll
      for (int n = 0; n < 4; ++n)
#pragma unroll
        for (int r = 0; r < 4; ++r)
          sA[(16 * m + crow + r) * 64 + 16 * n + rfrag] = acc[n][r];
    }
  } else {
#pragma unroll
    for (int mt = 0; mt < 2; ++mt) {
      const int m = w2 * 2 + mt;
      const int ra = 16 * m + rfrag;
      f32x4 acc[4] = {};
#pragma unroll
      for (int ks = 0; ks < 2; ++ks) {
        bf16x8 af = *(const bf16x8*)((const char*)sQ + swz128(ra, ks * 64 + koff * 2));
#pragma unroll
        for (int n = 0; n < 4; ++n) {
          bf16x8 bf = *(const bf16x8*)((const char*)sK + swz128(16 * n + rfrag, ks * 64 + koff * 2));
          acc[n] = __builtin_amdgcn_mfma_f32_16x16x32_bf16(af, bf, acc[n], 0, 0, 0);
        }
      }
#pragma unroll
      for (int n = 0; n < 4; ++n)
#pragma unroll
        for (int r = 0; r < 4; ++r) {
          int t = 16 * m + crow + r, j = 16 * n + rfrag;
          SLbuf[(long)blk * 4096 + t * 64 + j] = (j < t) ? f2bf(acc[n][r]) : (unsigned short)0;
        }
    }
  }
  __syncthreads();

  if (wid < 2) {
    const int d = lane;
    float x[64];
#pragma unroll
    for (int t = 0; t < 64; ++t) {
      float rhs;
      if (wid == 0) rhs = beta * bf2f(sV[t * 64 + d]);
      else          rhs = alpha * bf2f(*(const unsigned short*)((const char*)sK + swz128(t, 2 * d)));
      float s = 0.f;
#pragma unroll
      for (int j = 0; j < t; ++j) s = fmaf(sA[t * 64 + j], x[j], s);
      x[t] = rhs - alpha * s;
    }
    unsigned short* ob = (wid == 0 ? Ubuf : Wbuf) + (long)blk * 4096 + d;
#pragma unroll
    for (int t = 0; t < 64; ++t) ob[t * 64] = f2bf(x[t]);
  }
}

// ---------------- phase 2: sequential chunk recurrence ----------------
// Double-buffered tile set (Q/W/SL/KT/U) -> 2 barriers/chunk; staging of chunk
// c+1 overlaps chunk c's stage-B MFMAs. XCD-chunked block swizzle (T1).
__global__ __launch_bounds__(256) void chunk_scan(
    const unsigned short* __restrict__ qkv,
    const unsigned short* __restrict__ Ubuf, const unsigned short* __restrict__ Wbuf,
    const unsigned short* __restrict__ SLbuf,
    const float* __restrict__ state_in, unsigned short* __restrict__ ybuf,
    float* __restrict__ state_out) {
  // layout (bytes): buf k at k*34816: Q+0, W+8192, SL+16384, KT+24576, U+32768(2KB)
  // sGT at 69632 (2KB), sS at 71680 (2KB) -> 72KB total
  __shared__ __align__(16) char lds[73728];

  const int bid0 = blockIdx.x;
  const int blk = (bid0 & 7) * 32 + (bid0 >> 3);   // T1 (256 % 8 == 0)
  const int bh = blk >> 2, dq = blk & 3;
  const int b = bh >> 4, h = bh & 15;
  const int tid = threadIdx.x, wid = tid >> 6, lane = tid & 63;
  const int rfrag = lane & 15, koff = (lane >> 4) * 8, crow = (lane >> 4) * 4;
  const int row = tid >> 2, cg = tid & 3;

  char* gt = lds + 69632;
  char* ssb = lds + 71680;

  const unsigned short* gpb = qkv + (long)(b * 2048 + row) * 3072 + h * 64 + cg * 16;
  const long tbb = ((long)(bh * 32) * 64 + row) * 64 + cg * 16;
  const long ubb = ((long)(bh * 32) * 64 + (tid >> 1)) * 64 + dq * 16 + (tid & 1) * 8;

  bf16x8 qv0, qv1, kt0, kt1, wv0, wv1, sl0, sl1, uv;
#define LOADREGS(CN) do {                                                       \
    const unsigned short* gp = gpb + (long)(CN) * 64 * 3072;                    \
    const long tb = tbb + (long)(CN) * 4096;                                    \
    qv0 = *(const bf16x8*)gp;            qv1 = *(const bf16x8*)(gp + 8);        \
    kt0 = *(const bf16x8*)(gp + 2048);   kt1 = *(const bf16x8*)(gp + 2048 + 8); \
    wv0 = *(const bf16x8*)(Wbuf + tb);   wv1 = *(const bf16x8*)(Wbuf + tb + 8); \
    sl0 = *(const bf16x8*)(SLbuf + tb);  sl1 = *(const bf16x8*)(SLbuf + tb + 8);\
    if (tid < 128) uv = *(const bf16x8*)(Ubuf + ubb + (long)(CN) * 4096);       \
  } while (0)

#define WRITE_TILES(BUF) do {                                                   \
    char* bp = lds + (BUF) * 34816;                                             \
    *(bf16x8*)(bp + swz128(row, cg * 32)) = qv0;                                \
    *(bf16x8*)(bp + swz128(row, cg * 32 + 16)) = qv1;                           \
    *(bf16x8*)(bp + 8192 + swz128(row, cg * 32)) = wv0;                         \
    *(bf16x8*)(bp + 8192 + swz128(row, cg * 32 + 16)) = wv1;                    \
    *(bf16x8*)(bp + 16384 + swz128(row, cg * 32)) = sl0;                        \
    *(bf16x8*)(bp + 16384 + swz128(row, cg * 32 + 16)) = sl1;                   \
    *(bf16x8*)(bp + 24576 + swz128(row, cg * 32)) = kt0;                        \
    *(bf16x8*)(bp + 24576 + swz128(row, cg * 32 + 16)) = kt1;                   \
    if (tid < 128) *(bf16x8*)(bp + 32768 + ((tid >> 1) * 16 + (tid & 1) * 8) * 2) = uv; \
  } while (0)

  f32x4 sacc;
#pragma unroll
  for (int r = 0; r < 4; ++r)
    sacc[r] = state_in[(long)bh * 4096 + (dq * 16 + crow + r) * 64 + 16 * wid + rfrag];
#pragma unroll
  for (int r = 0; r < 4; ++r)
    *(unsigned short*)(ssb + swz128(crow + r, 2 * (16 * wid + rfrag))) = f2bf(sacc[r]);

  // prologue: stage chunk 0 into buf0; prefetch chunk 1 regs
  LOADREGS(0);
  WRITE_TILES(0);
  LOADREGS(1);
  LDS_BARRIER();

  for (int c = 0; c < NC_; ++c) {
    const int cur = c & 1;
    const char* bp = lds + cur * 34816;
    const int ta = 16 * wid + rfrag;

    // ---- stage A: P = W*S^T, Yq = Q*S^T; G = U - P -> sGT ----
    f32x4 p = {};
    f32x4 yac = {};
#pragma unroll
    for (int ks = 0; ks < 2; ++ks) {
      bf16x8 afw = *(const bf16x8*)(bp + 8192 + swz128(ta, ks * 64 + koff * 2));
      bf16x8 afq = *(const bf16x8*)(bp + swz128(ta, ks * 64 + koff * 2));
      bf16x8 bS = *(const bf16x8*)(ssb + swz128(rfrag, ks * 64 + koff * 2));
      p = __builtin_amdgcn_mfma_f32_16x16x32_bf16(afw, bS, p, 0, 0, 0);
      yac = __builtin_amdgcn_mfma_f32_16x16x32_bf16(afq, bS, yac, 0, 0, 0);
    }
#pragma unroll
    for (int r = 0; r < 4; ++r) {
      int t = 16 * wid + crow + r;
      float gg = bf2f(*(const unsigned short*)(bp + 32768 + (t * 16 + rfrag) * 2)) - p[r];
      *(unsigned short*)(gt + swz128(rfrag, 2 * t)) = f2bf(gg);
    }
    LDS_BARRIER();   // #2: GT produced -> consumed

    // ---- stage B: Y += SL*G ; S += G^T*K ; stage c+1 tiles (overlapped) ----
#pragma unroll
    for (int ks = 0; ks < 2; ++ks) {
      bf16x8 aSL = *(const bf16x8*)(bp + 16384 + swz128(ta, ks * 64 + koff * 2));
      bf16x8 bGT = *(const bf16x8*)(gt + swz128(rfrag, ks * 64 + koff * 2));
      yac = __builtin_amdgcn_mfma_f32_16x16x32_bf16(aSL, bGT, yac, 0, 0, 0);
    }
#pragma unroll
    for (int ks = 0; ks < 2; ++ks) {
      bf16x8 aGT = *(const bf16x8*)(gt + swz128(rfrag, ks * 64 + koff * 2));
      bf16x8 bKT = *(const bf16x8*)(bp + 24576 + swz128(16 * wid + rfrag, ks * 64 + koff * 2));
      sacc = __builtin_amdgcn_mfma_f32_16x16x32_bf16(aGT, bKT, sacc, 0, 0, 0);
    }
#pragma unroll
    for (int r = 0; r < 4; ++r) {
      int t = 16 * wid + crow + r;
      ybuf[(long)(b * 2048 + c * 64 + t) * 1024 + h * 64 + dq * 16 + rfrag] = f2bf(yac[r]);
    }
    // new S -> sS (read at next chunk's stage A, after boundary barrier)
#pragma unroll
    for (int r = 0; r < 4; ++r)
      *(unsigned short*)(ssb + swz128(crow + r, 2 * (16 * wid + rfrag))) = f2bf(sacc[r]);
    // stage chunk c+1 tiles into the other buffer; prefetch chunk c+2
    if (c + 1 < NC_) {
      WRITE_TILES(cur ^ 1);
      int cn = c + 2; if (cn > NC_ - 1) cn = NC_ - 1;
      LOADREGS(cn);
    }
    LDS_BARRIER();   // boundary: tiles staged + sS ready; reads of buf[cur] done
  }

#pragma unroll
  for (int r = 0; r < 4; ++r)
    state_out[(long)bh * 4096 + (dq * 16 + crow + r) * 64 + 16 * wid + rfrag] = sacc[r];
#undef LOADREGS
#undef WRITE_TILES
}

// ---------------- launch ----------------
extern "C" void kernel_launch(void* const* d_in, const int* in_sizes, int n_in,
                              void* d_out, int out_size, void* d_ws, size_t ws_size,
                              hipStream_t stream) {
  (void)in_sizes; (void)n_in; (void)out_size; (void)ws_size;
  const float* x     = (const float*)d_in[0];
  const float* Wq    = (const float*)d_in[1];
  const float* Wk    = (const float*)d_in[2];
  const float* Wv    = (const float*)d_in[3];
  const float* Wproj = (const float*)d_in[4];
  const float* a_raw = (const float*)d_in[5];
  const float* b_raw = (const float*)d_in[6];
  const float* state = (const float*)d_in[7];

  char* ws = (char*)d_ws;
  unsigned short* xbf = (unsigned short*)ws;                    // 16MB; reused as y
  unsigned short* W3  = (unsigned short*)(ws + (16l << 20));    // 6MB [Wq;Wk;Wv]
  unsigned short* Wp  = (unsigned short*)(ws + (22l << 20));    // 2MB
  unsigned short* qkv = (unsigned short*)(ws + (24l << 20));    // 48MB
  unsigned short* Ub  = (unsigned short*)(ws + (72l << 20));    // 16MB
  unsigned short* Wb  = (unsigned short*)(ws + (88l << 20));    // 16MB
  unsigned short* SLb = (unsigned short*)(ws + (104l << 20));   // 16MB -> 120MB total
  float* out = (float*)d_out;
  float* state_out = out + (long)B_ * T_ * C_;

  cvt_all<<<dim3(12288), dim3(256), 0, stream>>>(x, Wq, Wk, Wv, Wproj, xbf, W3, Wp);

  gemm256_bt<<<dim3(3072 / 256, 8192 / 256), dim3(512), 0, stream>>>(xbf, W3, qkv, 3072);

  chunk_prep<<<dim3(2048), dim3(256), 0, stream>>>(qkv, a_raw, b_raw, Ub, Wb, SLb);
  chunk_scan<<<dim3(256), dim3(256), 0, stream>>>(qkv, Ub, Wb, SLb, state, xbf, state_out);

  gemm_bt<0><<<dim3(1024 / 128, 8192 / 128), dim3(256), 0, stream>>>(xbf, Wp, (void*)out, 8192, 1024, 1024);
}